// Round 5
// baseline (792.975 us; speedup 1.0000x reference)
//
#include <hip/hip_runtime.h>
#include <math.h>

// ---------------------------------------------------------------------------
// TGAT classifier. Algebraic folding (score/aggregate in input space,
// wq/wk/wv/W_lin/fc_w folded into SW/F), f16 MFMA everywhere.
// Round 5: k_score4 (wave-per-row, barrier-free), k_tail (fused
// P-GEMM+LN+MergeLayer, direct-L2 B-fragments), zb split-K, launch folding.
// ---------------------------------------------------------------------------

typedef _Float16 h4 __attribute__((ext_vector_type(4)));
typedef _Float16 h8 __attribute__((ext_vector_type(8)));
typedef float f4 __attribute__((ext_vector_type(4)));

// ---------------- setup fold kernels ----------------

__global__ __launch_bounds__(256) void k_prep1(
    const float* __restrict__ phase, const float* __restrict__ wq,
    float* __restrict__ te0, float* __restrict__ bq)
{
  int l = blockIdx.x, t = threadIdx.x;
  __shared__ float te[128];
  if (t < 128) te[t] = cosf(phase[t]);
  __syncthreads();
  if (l == 0 && t < 128) te0[t] = te[t];
  const float* wr = wq + ((size_t)l * 256 + t) * 256 + 128;
  float s = 0.f;
  for (int k = 0; k < 128; k++) s += wr[k] * te[k];
  bq[l * 256 + t] = s;
}

__global__ __launch_bounds__(256) void k_prep2(
    const float* __restrict__ wk, const float* __restrict__ bq, float* __restrict__ cbf)
{
  int lh = blockIdx.x, l = lh >> 1, h = lh & 1, e = threadIdx.x;
  const float* wkb = wk + (size_t)l * 65536 + (size_t)h * 128 * 256;
  const float* bqb = bq + l * 256 + h * 128;
  float s = 0.f;
  for (int d = 0; d < 128; d++) s += wkb[(size_t)d * 256 + e] * bqb[d];
  cbf[lh * 256 + e] = s;
}

__global__ __launch_bounds__(256) void k_prepM(
    const float* __restrict__ wq, const float* __restrict__ wk, float* __restrict__ Mb)
{
  int lh = blockIdx.y, l = lh >> 1, h = lh & 1;
  int idx = blockIdx.x * 256 + threadIdx.x;   // < 256*128
  int e = idx >> 7, s = idx & 127;
  const float* wkb = wk + (size_t)l * 65536 + (size_t)h * 128 * 256;
  const float* wqb = wq + (size_t)l * 65536 + (size_t)h * 128 * 256;
  float acc = 0.f;
  for (int d = 0; d < 128; d++) acc += wkb[(size_t)d * 256 + e] * wqb[(size_t)d * 256 + s];
  Mb[(size_t)lh * 32768 + idx] = acc;
}

__global__ __launch_bounds__(256) void k_build_SW(
    _Float16* __restrict__ SWa, float* __restrict__ cba,
    const float* __restrict__ Mb, const float* __restrict__ cbf,
    const float* __restrict__ Wlin, const float* __restrict__ blin)
{
  int ci = blockIdx.y;
  int lyr = (ci == 2) ? 1 : 0;
  int ul  = (ci == 0) ? 1 : 0;
  const float* M2 = Mb + (size_t)lyr * 2 * 32768;
  const float* c2 = cbf + (size_t)lyr * 512;
  _Float16* SW = SWa + (size_t)ci * 520 * 128;
  float* cb = cba + (size_t)ci * 520;
  int idx = blockIdx.x * 256 + threadIdx.x;
  if (idx >= 520 * 128) return;
  int urow = idx / 128, s = idx % 128;
  int h = urow / 260, u = urow % 260;
  const float* M = M2 + (size_t)h * 32768;
  const float* c = c2 + h * 256;
  float val = 0.f, cbv = 0.f;
  if (u < 128) {
    if (ul) {
      for (int cc = 0; cc < 128; cc++) {
        float w = Wlin[cc * 128 + u];
        val += w * M[cc * 128 + s];
        cbv += w * c[cc];
      }
    } else { val = M[u * 128 + s]; cbv = c[u]; }
  } else if (u < 256) {
    val = M[u * 128 + s]; cbv = c[u];
  } else if (u == 256) {
    if (ul) {
      for (int cc = 0; cc < 128; cc++) {
        float w = blin[cc];
        val += w * M[cc * 128 + s];
        cbv += w * c[cc];
      }
    }
  }
  SW[(size_t)urow * 128 + s] = (_Float16)val;
  if (s == 0) cb[urow] = cbv;
}

__global__ __launch_bounds__(256) void k_build_OW(
    float* __restrict__ OWa, const float* __restrict__ wv,
    const float* __restrict__ Wlin, const float* __restrict__ blin)
{
  int ci = blockIdx.y;
  int lyr = (ci == 2) ? 1 : 0;
  int ul  = (ci == 0) ? 1 : 0;
  float* OW = OWa + (size_t)ci * 2 * 128 * 260;
  const float* wvl = wv + (size_t)lyr * 65536;
  int idx = blockIdx.x * 256 + threadIdx.x;
  if (idx >= 2 * 128 * 260) return;
  int u = idx % 260; int d = (idx / 260) % 128; int h = idx / (260 * 128);
  const float* wr = wvl + (size_t)(h * 128 + d) * 256;
  float val = 0.f;
  if (u < 128) {
    if (ul) { for (int cc = 0; cc < 128; cc++) val += wr[cc] * Wlin[cc * 128 + u]; }
    else val = wr[u];
  } else if (u < 256) {
    val = wr[u];
  } else if (u == 256) {
    if (ul) { for (int cc = 0; cc < 128; cc++) val += wr[cc] * blin[cc]; }
  }
  OW[idx] = val;
}

__global__ __launch_bounds__(256) void k_build_F(
    _Float16* __restrict__ Fa, const float* __restrict__ fcw, const float* __restrict__ OWa)
{
  int ci = blockIdx.y >> 1, h = blockIdx.y & 1;
  int lyr = (ci == 2) ? 1 : 0;
  int idx = blockIdx.x * 256 + threadIdx.x;   // < 256*260
  int p = idx / 260, u = idx % 260;
  const float* fw = fcw + (size_t)lyr * 65536 + (size_t)p * 256 + h * 128;
  const float* ow = OWa + (size_t)ci * 2 * 128 * 260 + (size_t)h * 128 * 260;
  float s = 0.f;
  for (int d = 0; d < 128; d++) s += fw[d] * ow[(size_t)d * 260 + u];
  Fa[(size_t)ci * 256 * 520 + (size_t)p * 520 + h * 260 + u] = (_Float16)s;
}

// one launch: W_lin,m1w,m2w f2h + W_gc transpose-f2h + lacc zero
__global__ __launch_bounds__(256) void k_convert(
    const float* __restrict__ Wlin, const float* __restrict__ m1w,
    const float* __restrict__ m2w, const float* __restrict__ Wgc,
    _Float16* __restrict__ Wlinh, _Float16* __restrict__ m1wh,
    _Float16* __restrict__ m2wh, _Float16* __restrict__ WgcTh,
    float* __restrict__ lacc)
{
  int idx = blockIdx.x * 256 + threadIdx.x;
  if (idx == 0) lacc[0] = 0.f;
  int i = idx;
  if (i < 16384) { Wlinh[i] = (_Float16)Wlin[i]; return; }
  i -= 16384;
  if (i < 98304) { m1wh[i] = (_Float16)m1w[i]; return; }
  i -= 98304;
  if (i < 32768) { m2wh[i] = (_Float16)m2w[i]; return; }
  i -= 32768;
  if (i < 16384) {
    int c = i >> 7, r = i & 127;
    WgcTh[i] = (_Float16)Wgc[(size_t)r * 128 + c];
  }
}

// ---------------- generic f16 MFMA GEMM: C[M,N] = A[M,K](f32) @ Bh[N,K].T
// (+bias f32). cmode: 0 f32 store (+split-K partials via blockIdx.z),
// 1 f16 store, 2 f16 transposed store (C[N][ldc]). M % BM == 0.

template<int BM, int BN>
__global__ __launch_bounds__(256) void k_mgemm(
    const float* __restrict__ A, int lda,
    const _Float16* __restrict__ Bh, int ldb,
    const float* __restrict__ bias,
    float* __restrict__ C, int ldc,
    int M, int N, int K, int cmode, int klen)
{
  constexpr int BK = 64;
  constexpr int LDS = BK + 8;
  __shared__ _Float16 As[BM][LDS];
  __shared__ _Float16 Bs[BN][LDS];
  constexpr int FM = BM / 32;
  constexpr int FN = BN / 32;
  int tid = threadIdx.x;
  int wv = tid >> 6, lane = tid & 63;
  int wm = wv >> 1, wn = wv & 1;
  int row0 = blockIdx.x * BM, col0 = blockIdx.y * BN;
  int m0 = wm * (BM / 2), n0 = wn * (BN / 2);
  int lr = lane & 15, lk = lane >> 4;
  int z = blockIdx.z;
  int kbeg = z * klen;
  int kend = kbeg + klen; if (kend > K) kend = K;

  f4 acc[FM][FN];
#pragma unroll
  for (int i = 0; i < FM; i++)
#pragma unroll
    for (int j = 0; j < FN; j++) acc[i][j] = (f4)0.f;

  constexpr int TPRA = 256 / BM;
  constexpr int F4A = (BK / TPRA) / 4;
  int arow = tid / TPRA;
  int acol = (tid % TPRA) * (BK / TPRA);
  constexpr int TPRB = 256 / BN;
  constexpr int F4B = (BK / TPRB) / 4;
  int brow = tid / TPRB;
  int bcol = (tid % TPRB) * (BK / TPRB);
  int gar = row0 + arow;
  int gbr = col0 + brow;
  bool bvalid = gbr < N;

  for (int k0 = kbeg; k0 < kend; k0 += BK) {
    __syncthreads();
#pragma unroll
    for (int j = 0; j < F4A; j++) {
      int ka = k0 + acol + j * 4;
      f4 v = (f4)0.f;
      if (ka < K) v = *(const f4*)&A[(size_t)gar * lda + ka];
      h4 hv = { (_Float16)v.x, (_Float16)v.y, (_Float16)v.z, (_Float16)v.w };
      *(h4*)&As[arow][acol + j * 4] = hv;
    }
#pragma unroll
    for (int j = 0; j < F4B; j++) {
      int ka = k0 + bcol + j * 4;
      h4 hv = (h4)(_Float16)0.f;
      if (bvalid && ka < K) hv = *(const h4*)&Bh[(size_t)gbr * ldb + ka];
      *(h4*)&Bs[brow][bcol + j * 4] = hv;
    }
    __syncthreads();
#pragma unroll
    for (int kk = 0; kk < 2; kk++) {
      h8 af[FM], bf[FN];
#pragma unroll
      for (int i = 0; i < FM; i++)
        af[i] = *(h8*)&As[m0 + i * 16 + lr][kk * 32 + lk * 8];
#pragma unroll
      for (int j = 0; j < FN; j++)
        bf[j] = *(h8*)&Bs[n0 + j * 16 + lr][kk * 32 + lk * 8];
#pragma unroll
      for (int i = 0; i < FM; i++)
#pragma unroll
        for (int j = 0; j < FN; j++)
          acc[i][j] = __builtin_amdgcn_mfma_f32_16x16x32_f16(af[i], bf[j], acc[i][j], 0, 0, 0);
    }
  }
  float* Cz = C + (size_t)z * M * ldc;   // split-K partial offset (cmode 0)
#pragma unroll
  for (int j = 0; j < FN; j++) {
    int c = col0 + n0 + j * 16 + lr;
    if (c >= N) continue;
    float bz = (bias && z == 0) ? bias[c] : 0.f;
#pragma unroll
    for (int i = 0; i < FM; i++) {
      int rbase = row0 + m0 + i * 16 + lk * 4;
#pragma unroll
      for (int r = 0; r < 4; r++) {
        int rr = rbase + r;
        float v = acc[i][j][r] + bz;
        if (cmode == 0) Cz[(size_t)rr * ldc + c] = v;
        else if (cmode == 1) ((_Float16*)C)[(size_t)rr * ldc + c] = (_Float16)v;
        else ((_Float16*)C)[(size_t)c * ldc + rr] = (_Float16)v;
      }
    }
  }
}

// sum split-K partials -> f16
__global__ __launch_bounds__(256) void k_zcomb(
    const float* __restrict__ zp, _Float16* __restrict__ zh, int n4)
{
  int i = blockIdx.x * 256 + threadIdx.x;
  if (i >= n4) return;
  f4 a = ((const f4*)zp)[i];
  f4 b = ((const f4*)(zp))[n4 + i];
  h4 o = { (_Float16)(a.x + b.x), (_Float16)(a.y + b.y),
           (_Float16)(a.z + b.z), (_Float16)(a.w + b.w) };
  ((h4*)zh)[i] = o;
}

// ---------------- score/softmax/aggregate: 4 rows/block, wave-per-row -------
// Wave-private LDS slices; no __syncthreads (DS ops in a wave are in-order;
// wave_barrier stops compiler reordering).

__global__ __launch_bounds__(256) void k_score4(
    _Float16* __restrict__ UY,
    const float* __restrict__ feat,   // [rows][20][128] f32
    const float* __restrict__ tsrc,
    const float* __restrict__ tngh,
    const int*   __restrict__ idx,
    const float* __restrict__ freq, const float* __restrict__ phase,
    int rows)
{
  __shared__ _Float16 fsh[4][20][136];
  __shared__ _Float16 tesh[4][20][136];
  __shared__ _Float16 ush[4][536];     // head h at h*264; sb at h*264+256
  __shared__ float ssh[4][2][20];
  __shared__ float ash[4][2][20];
  __shared__ float dtsh[4][20];
  __shared__ int   msh[4][20];
  int tid = threadIdx.x;
  int w = tid >> 6, lane = tid & 63;
  int row = blockIdx.x * 4 + w;
  if (row >= rows) return;

  // stage: dt/mask, U (f16, repacked), feat (f32->f16)
  if (lane < 20) {
    dtsh[w][lane] = tsrc[row] - tngh[(size_t)row * 20 + lane];
    msh[w][lane] = (idx[(size_t)row * 20 + lane] == 0);
  }
  for (int u = lane; u < 520; u += 64) {
    int pos = (u < 260) ? u : u + 4;
    ush[w][pos] = UY[(size_t)row * 520 + u];
  }
  const float4* fg = (const float4*)(feat + (size_t)row * 2560);
  for (int i = lane; i < 640; i += 64) {
    int j = i >> 5, c4 = i & 31;
    float4 v = fg[i];
    h4 hv = { (_Float16)v.x, (_Float16)v.y, (_Float16)v.z, (_Float16)v.w };
    *(h4*)&fsh[w][j][c4 * 4] = hv;
  }
  __builtin_amdgcn_wave_barrier();
  for (int i = lane; i < 2560; i += 64) {
    int j = i >> 7, t = i & 127;
    tesh[w][j][t] = (_Float16)__cosf(dtsh[w][j] * freq[t] + phase[t]);
  }
  __builtin_amdgcn_wave_barrier();

  // dots: 16-lane groups, 4 tasks in parallel x 10 iters (40 = 2 heads x 20)
  int g = lane >> 4, li = lane & 15;
#pragma unroll
  for (int it = 0; it < 10; it++) {
    int t = it * 4 + g;
    int h = t / 20, j = t % 20;
    const _Float16* xp = (li < 8) ? &fsh[w][j][li * 16] : &tesh[w][j][(li - 8) * 16];
    const _Float16* up = &ush[w][h * 264 + li * 16];
    h8 x0 = *(const h8*)xp, x1 = *(const h8*)(xp + 8);
    h8 u0 = *(const h8*)up, u1 = *(const h8*)(up + 8);
    float part = 0.f;
#pragma unroll
    for (int e = 0; e < 8; e++)
      part += (float)x0[e] * (float)u0[e] + (float)x1[e] * (float)u1[e];
    for (int m = 8; m; m >>= 1) part += __shfl_xor(part, m, 16);
    if (li == 0) ssh[w][h][j] = part + (float)ush[w][h * 264 + 256];
  }
  __builtin_amdgcn_wave_barrier();

  // softmax: half-wave per head
  {
    int head = lane >> 5, l2 = lane & 31;
    const float scale = 0.08838834764831845f; // 1/sqrt(128)
    float s = (l2 < 20) ? (msh[w][l2] ? -1e10f : ssh[w][head][l2] * scale) : -3.0e38f;
    float mx = s;
    for (int m = 16; m; m >>= 1) mx = fmaxf(mx, __shfl_xor(mx, m, 32));
    float e = (l2 < 20) ? __expf(s - mx) : 0.f;
    float sum = e;
    for (int m = 16; m; m >>= 1) sum += __shfl_xor(sum, m, 32);
    if (l2 < 20) ash[w][head][l2] = e / sum;
  }
  __builtin_amdgcn_wave_barrier();

  // aggregate: lane owns 4 cols for both heads
  {
    int c = lane * 4;
    float a0[4] = {0.f, 0.f, 0.f, 0.f}, a1[4] = {0.f, 0.f, 0.f, 0.f};
#pragma unroll 5
    for (int j = 0; j < 20; j++) {
      float w0 = ash[w][0][j], w1 = ash[w][1][j];
      h4 x = (c < 128) ? *(const h4*)&fsh[w][j][c] : *(const h4*)&tesh[w][j][c - 128];
#pragma unroll
      for (int e = 0; e < 4; e++) {
        float xf = (float)x[e];
        a0[e] += w0 * xf; a1[e] += w1 * xf;
      }
    }
    h4 o0 = { (_Float16)a0[0], (_Float16)a0[1], (_Float16)a0[2], (_Float16)a0[3] };
    h4 o1 = { (_Float16)a1[0], (_Float16)a1[1], (_Float16)a1[2], (_Float16)a1[3] };
    *(h4*)&UY[(size_t)row * 520 + c] = o0;
    *(h4*)&UY[(size_t)row * 520 + 260 + c] = o1;
    if (lane == 0) {
      h4 pad = { (_Float16)1.f, (_Float16)0.f, (_Float16)0.f, (_Float16)0.f };
      *(h4*)&UY[(size_t)row * 520 + 256] = pad;
      *(h4*)&UY[(size_t)row * 520 + 516] = pad;
    }
  }
}

// ---------------- fused tail: P-GEMM + residual + LN + MergeLayer -----------
// per block: 64 rows. P = U@F.T (+fcb+q, LN) -> LDS f16; H = relu([P|src]@m1w.T
// + m1b) -> LDS; out = H@m2w.T + m2b (f32). B-frags direct from L2.

__global__ __launch_bounds__(256) void k_tail(
    const _Float16* __restrict__ U,   // [rows][520]
    const _Float16* __restrict__ F,   // [256][520]
    const float* __restrict__ fcb,
    const float* __restrict__ srcv,   // [rows][128] f32
    const float* __restrict__ te0,
    const float* __restrict__ lng, const float* __restrict__ lnb,
    const _Float16* __restrict__ m1w, // [128][384]
    const float* __restrict__ m1b,
    const _Float16* __restrict__ m2w, // [128][128]
    const float* __restrict__ m2b,
    float* __restrict__ outp, int rows)
{
  __shared__ _Float16 Ps[64][264];
  __shared__ _Float16 Ss[64][136];    // src f16; reused as H after m1
  __shared__ float redS[64][4], redQ[64][4];
  __shared__ float mrow[64], rrow[64];
  int tid = threadIdx.x;
  int wv = tid >> 6, lane = tid & 63;
  int lr = lane & 15, lk = lane >> 4;
  int row0 = blockIdx.x * 64;
  int n0 = wv * 64;

  // stage src f32 -> f16 (m1 phase, k=256..383)
  {
    const float4* sg = (const float4*)(srcv + (size_t)row0 * 128);
    for (int i = tid; i < 2048; i += 256) {
      int rr = i >> 5, c4 = i & 31;
      float4 v = sg[i];
      h4 hv = { (_Float16)v.x, (_Float16)v.y, (_Float16)v.z, (_Float16)v.w };
      *(h4*)&Ss[rr][c4 * 4] = hv;
    }
  }

  // phase 1: P-GEMM (64x256, K=520), fragments direct from global (L2)
  f4 acc[4][4];
#pragma unroll
  for (int i = 0; i < 4; i++)
#pragma unroll
    for (int j = 0; j < 4; j++) acc[i][j] = (f4)0.f;
  for (int kt = 0; kt < 17; kt++) {
    int kb = kt * 32 + lk * 8;
    bool ok = (kb + 8 <= 520);
    h8 af[4], bf[4];
#pragma unroll
    for (int i = 0; i < 4; i++)
      af[i] = ok ? *(const h8*)&U[(size_t)(row0 + i * 16 + lr) * 520 + kb]
                 : (h8)(_Float16)0.f;
#pragma unroll
    for (int j = 0; j < 4; j++)
      bf[j] = ok ? *(const h8*)&F[(size_t)(n0 + j * 16 + lr) * 520 + kb]
                 : (h8)(_Float16)0.f;
#pragma unroll
    for (int i = 0; i < 4; i++)
#pragma unroll
      for (int j = 0; j < 4; j++)
        acc[i][j] = __builtin_amdgcn_mfma_f32_16x16x32_f16(af[i], bf[j], acc[i][j], 0, 0, 0);
  }

  // epilogue: + fcb + q, row-reduce for LN
#pragma unroll
  for (int i = 0; i < 4; i++) {
#pragma unroll
    for (int r = 0; r < 4; r++) {
      int row_l = i * 16 + lk * 4 + r;
      float rs = 0.f, rq = 0.f;
#pragma unroll
      for (int j = 0; j < 4; j++) {
        int c = n0 + j * 16 + lr;
        float q = (c < 128) ? srcv[(size_t)(row0 + row_l) * 128 + c] : te0[c - 128];
        float v = acc[i][j][r] + fcb[c] + q;
        acc[i][j][r] = v;
        rs += v; rq += v * v;
      }
      for (int m = 8; m; m >>= 1) {
        rs += __shfl_xor(rs, m, 16);
        rq += __shfl_xor(rq, m, 16);
      }
      if (lr == 0) { redS[row_l][wv] = rs; redQ[row_l][wv] = rq; }
    }
  }
  __syncthreads();
  if (tid < 64) {
    float s4 = redS[tid][0] + redS[tid][1] + redS[tid][2] + redS[tid][3];
    float q4 = redQ[tid][0] + redQ[tid][1] + redQ[tid][2] + redQ[tid][3];
    float mean = s4 * (1.0f / 256.0f);
    float var = q4 * (1.0f / 256.0f) - mean * mean;
    mrow[tid] = mean;
    rrow[tid] = rsqrtf(var + 1e-5f);
  }
  __syncthreads();
#pragma unroll
  for (int i = 0; i < 4; i++) {
#pragma unroll
    for (int r = 0; r < 4; r++) {
      int row_l = i * 16 + lk * 4 + r;
      float mean = mrow[row_l], rstd = rrow[row_l];
#pragma unroll
      for (int j = 0; j < 4; j++) {
        int c = n0 + j * 16 + lr;
        Ps[row_l][c] = (_Float16)((acc[i][j][r] - mean) * rstd * lng[c] + lnb[c]);
      }
    }
  }
  __syncthreads();

  // phase 2: m1 (64x128, K=384: [Ps|Ss]); B-frags from global m1w
  int wm = wv >> 1, wn = wv & 1;
  f4 a2[2][4];
#pragma unroll
  for (int i = 0; i < 2; i++)
#pragma unroll
    for (int j = 0; j < 4; j++) a2[i][j] = (f4)0.f;
  for (int kk = 0; kk < 12; kk++) {
    int kb = kk * 32 + lk * 8;
    h8 af[2], bf[4];
#pragma unroll
    for (int i = 0; i < 2; i++) {
      int rl = wm * 32 + i * 16 + lr;
      af[i] = (kb < 256) ? *(const h8*)&Ps[rl][kb] : *(const h8*)&Ss[rl][kb - 256];
    }
#pragma unroll
    for (int j = 0; j < 4; j++)
      bf[j] = *(const h8*)&m1w[(size_t)(wn * 64 + j * 16 + lr) * 384 + kb];
#pragma unroll
    for (int i = 0; i < 2; i++)
#pragma unroll
      for (int j = 0; j < 4; j++)
        a2[i][j] = __builtin_amdgcn_mfma_f32_16x16x32_f16(af[i], bf[j], a2[i][j], 0, 0, 0);
  }
  __syncthreads();   // everyone done reading Ss before H overwrites it
#pragma unroll
  for (int i = 0; i < 2; i++) {
#pragma unroll
    for (int j = 0; j < 4; j++) {
      int c = wn * 64 + j * 16 + lr;
      float bz = m1b[c];
#pragma unroll
      for (int r = 0; r < 4; r++) {
        float v = a2[i][j][r] + bz;
        if (v < 0.f) v = 0.f;
        Ss[wm * 32 + i * 16 + lk * 4 + r][c] = (_Float16)v;   // H
      }
    }
  }
  __syncthreads();

  // phase 3: m2 (64x128, K=128); B-frags from global m2w
  f4 a3[2][4];
#pragma unroll
  for (int i = 0; i < 2; i++)
#pragma unroll
    for (int j = 0; j < 4; j++) a3[i][j] = (f4)0.f;
#pragma unroll
  for (int kk = 0; kk < 4; kk++) {
    int kb = kk * 32 + lk * 8;
    h8 af[2], bf[4];
#pragma unroll
    for (int i = 0; i < 2; i++)
      af[i] = *(const h8*)&Ss[wm * 32 + i * 16 + lr][kb];
#pragma unroll
    for (int j = 0; j < 4; j++)
      bf[j] = *(const h8*)&m2w[(size_t)(wn * 64 + j * 16 + lr) * 128 + kb];
#pragma unroll
    for (int i = 0; i < 2; i++)
#pragma unroll
      for (int j = 0; j < 4; j++)
        a3[i][j] = __builtin_amdgcn_mfma_f32_16x16x32_f16(af[i], bf[j], a3[i][j], 0, 0, 0);
  }
#pragma unroll
  for (int j = 0; j < 4; j++) {
    int c = wn * 64 + j * 16 + lr;
    float bz = m2b[c];
#pragma unroll
    for (int i = 0; i < 2; i++) {
#pragma unroll
      for (int r = 0; r < 4; r++) {
        int rl = wm * 32 + i * 16 + lk * 4 + r;
        outp[(size_t)(row0 + rl) * 128 + c] = a3[i][j][r] + bz;
      }
    }
  }
}

// ---------------- fused MFMA autoencoder loss --------------------------------

__global__ __launch_bounds__(256) void k_loss_mfma(
    const _Float16* __restrict__ z, const float* __restrict__ adj,
    float* __restrict__ acc)
{
  int tid = threadIdx.x;
  int wv = tid >> 6, lane = tid & 63;
  int wm = wv >> 1, wn = wv & 1;
  int lr = lane & 15, lk = lane >> 4;
  int row0 = blockIdx.x * 128 + wm * 64;
  int col0 = blockIdx.y * 128 + wn * 64;

  f4 accf[4][4];
#pragma unroll
  for (int i = 0; i < 4; i++)
#pragma unroll
    for (int j = 0; j < 4; j++) accf[i][j] = (f4)0.f;

#pragma unroll
  for (int kk = 0; kk < 4; kk++) {
    int ko = kk * 32 + lk * 8;
    h8 af[4], bf[4];
#pragma unroll
    for (int i = 0; i < 4; i++)
      af[i] = *(const h8*)&z[(size_t)(row0 + i * 16 + lr) * 128 + ko];
#pragma unroll
    for (int j = 0; j < 4; j++)
      bf[j] = *(const h8*)&z[(size_t)(col0 + j * 16 + lr) * 128 + ko];
#pragma unroll
    for (int i = 0; i < 4; i++)
#pragma unroll
      for (int j = 0; j < 4; j++)
        accf[i][j] = __builtin_amdgcn_mfma_f32_16x16x32_f16(af[i], bf[j], accf[i][j], 0, 0, 0);
  }

  float lsum = 0.f;
#pragma unroll
  for (int i = 0; i < 4; i++) {
    int rbase = row0 + i * 16 + lk * 4;
#pragma unroll
    for (int r = 0; r < 4; r++) {
      const float* arow = adj + (size_t)(rbase + r) * 4096;
#pragma unroll
      for (int j = 0; j < 4; j++) {
        float x = accf[i][j][r];
        float s = 1.0f / (1.0f + __expf(-x));
        float d = arow[col0 + j * 16 + lr] - s;
        lsum += d * d;
      }
    }
  }
  for (int m = 32; m; m >>= 1) lsum += __shfl_xor(lsum, m, 64);
  if (lane == 0) atomicAdd(acc, lsum);
}

__global__ void k_final(const float* acc, float* out) {
  out[0] = acc[0] * (1.0f / (4096.0f * 4096.0f));
}

// ---------------------------------------------------------------------------

extern "C" void kernel_launch(void* const* d_in, const int* in_sizes, int n_in,
                              void* d_out, int out_size, void* d_ws, size_t ws_size,
                              hipStream_t stream) {
  const float* src_feat  = (const float*)d_in[0];
  const float* src_t     = (const float*)d_in[1];
  const int*   ngh1_idx  = (const int*)d_in[2];
  const float* ngh1_t    = (const float*)d_in[3];
  const float* ngh1_feat = (const float*)d_in[4];
  const int*   ngh2_idx  = (const int*)d_in[5];
  const float* ngh2_t    = (const float*)d_in[6];
  const float* ngh2_feat = (const float*)d_in[7];
  const float* ae_x      = (const float*)d_in[8];
  const float* ae_adj    = (const float*)d_in[9];
  const float* W_lin     = (const float*)d_in[10];
  const float* b_lin     = (const float*)d_in[11];
  const float* freq      = (const float*)d_in[12];
  const float* phase     = (const float*)d_in[13];
  const float* wq        = (const float*)d_in[14];
  const float* wk        = (const float*)d_in[15];
  const float* wv        = (const float*)d_in[16];
  const float* fcw       = (const float*)d_in[17];
  const float* fcb       = (const float*)d_in[18];
  const float* lng       = (const float*)d_in[19];
  const float* lnb       = (const float*)d_in[20];
  const float* m1w       = (const float*)d_in[21];
  const float* m1b       = (const float*)d_in[22];
  const float* m2w       = (const float*)d_in[23];
  const float* m2b       = (const float*)d_in[24];
  const float* W_gc      = (const float*)d_in[25];
  const float* b_gc      = (const float*)d_in[26];
  float* out = (float*)d_out;

  const int NB = 2048, NA = 40960;

  char* w = (char*)d_ws;
  size_t off = 0;
  auto alloc = [&](size_t bytes) -> void* {
    void* p = (void*)(w + off);
    off += (bytes + 255) & ~(size_t)255;
    return p;
  };
  float* te0    = (float*)alloc(128 * 4);
  float* linS   = (float*)alloc((size_t)NB * 128 * 4);
  float* lin1   = (float*)alloc((size_t)NA * 128 * 4);
  float* src_l1 = (float*)alloc((size_t)NB * 128 * 4);
  float* ngh_l1 = (float*)alloc((size_t)NA * 128 * 4);
  float* bq     = (float*)alloc(2 * 256 * 4);
  float* Mb     = (float*)alloc((size_t)2 * 2 * 256 * 128 * 4);
  float* cbf    = (float*)alloc(2 * 2 * 256 * 4);
  _Float16* SWh = (_Float16*)alloc((size_t)3 * 520 * 128 * 2);
  float* cbU    = (float*)alloc(3 * 520 * 4);
  float* OW     = (float*)alloc((size_t)3 * 2 * 128 * 260 * 4);
  _Float16* Fh  = (_Float16*)alloc((size_t)3 * 256 * 520 * 2);
  _Float16* Wlinh = (_Float16*)alloc(16384 * 2);
  _Float16* m1wh  = (_Float16*)alloc((size_t)2 * 128 * 384 * 2);
  _Float16* m2wh  = (_Float16*)alloc((size_t)2 * 128 * 128 * 2);
  _Float16* WgcTh = (_Float16*)alloc(16384 * 2);
  _Float16* xwTh  = (_Float16*)alloc((size_t)4096 * 128 * 2);
  float* zpart    = (float*)alloc((size_t)2 * 4096 * 128 * 4);
  _Float16* zh    = (_Float16*)alloc((size_t)4096 * 128 * 2);
  float* lacc   = (float*)alloc(256);
  size_t fixed = off;

  size_t avail = (ws_size > fixed) ? (ws_size - fixed) : 0;
  long rows_c = (long)(avail / 1100);   // 520*2 B/row + margin
  if (rows_c > NA) rows_c = NA;
  rows_c &= ~127L;
  if (rows_c < 2048) rows_c = 2048;
  _Float16* Ubuf = (_Float16*)alloc((size_t)rows_c * 520 * 2);

  auto gemm128 = [&](const float* A, int lda, const _Float16* Bm, int ldb,
                     const float* bias, float* Cm, int ldc,
                     int M, int N, int Kd, int cmode) {
    dim3 g(M / 128, (N + 127) / 128);
    k_mgemm<128, 128><<<g, 256, 0, stream>>>(A, lda, Bm, ldb, bias, Cm, ldc,
                                             M, N, Kd, cmode, Kd);
  };

  // ---- folded weights (7 launches) ----
  k_prep1<<<2, 256, 0, stream>>>(phase, wq, te0, bq);
  k_prep2<<<4, 256, 0, stream>>>(wk, bq, cbf);
  k_prepM<<<dim3(128, 4), 256, 0, stream>>>(wq, wk, Mb);
  k_build_SW<<<dim3(260, 3), 256, 0, stream>>>(SWh, cbU, Mb, cbf, W_lin, b_lin);
  k_build_OW<<<dim3(260, 3), 256, 0, stream>>>(OW, wv, W_lin, b_lin);
  k_build_F<<<dim3(260, 6), 256, 0, stream>>>(Fh, fcw, OW);
  k_convert<<<640, 256, 0, stream>>>(W_lin, m1w, m2w, W_gc, Wlinh, m1wh, m2wh,
                                     WgcTh, lacc);

  // ---- feature linear layers ----
  gemm128(src_feat, 128, Wlinh, 128, b_lin, linS, 128, NB, 128, 128, 0);
  gemm128(ngh1_feat, 128, Wlinh, 128, b_lin, lin1, 128, NA, 128, 128, 0);

  // ---- attention calls: U-GEMM -> score4 -> tail ----
  auto attn_call = [&](int ci, long rows_total, const float* srcvec,
                       const float* featp, const float* tsrcp, const float* tnghp,
                       const int* idxp, int l, float* outp) {
    for (long r0 = 0; r0 < rows_total; r0 += rows_c) {
      long rem = rows_total - r0;
      int rows = (int)(rem < rows_c ? rem : rows_c);
      gemm128(srcvec + r0 * 128, 128, SWh + (size_t)ci * 520 * 128, 128,
              cbU + ci * 520, (float*)Ubuf, 520, rows, 520, 128, 1);
      k_score4<<<rows / 4, 256, 0, stream>>>(Ubuf, featp + r0 * 2560, tsrcp + r0,
                                             tnghp + r0 * 20, idxp + r0 * 20,
                                             freq, phase, rows);
      k_tail<<<rows / 64, 256, 0, stream>>>(
          Ubuf, Fh + (size_t)ci * 256 * 520, fcb + l * 256, srcvec + r0 * 128,
          te0, lng + l * 256, lnb + l * 256,
          m1wh + (size_t)l * 128 * 384, m1b + l * 128,
          m2wh + (size_t)l * 128 * 128, m2b + l * 128, outp + r0 * 128, rows);
    }
  };
  attn_call(0, NA, lin1, ngh2_feat, ngh1_t, ngh2_t, ngh2_idx, 0, ngh_l1);
  attn_call(1, NB, linS, lin1, src_t, ngh1_t, ngh1_idx, 0, src_l1);
  attn_call(2, NB, src_l1, ngh_l1, src_t, ngh1_t, ngh1_idx, 1, out);

  // ---- autoencoder loss ----
  // xw^T directly via transposed f16 store (cmode 2, ldc = 4096)
  {
    dim3 g(4096 / 128, 1);
    k_mgemm<128, 128><<<g, 256, 0, stream>>>(ae_x, 128, WgcTh, 128, nullptr,
                                             (float*)xwTh, 4096, 4096, 128, 128, 2, 128);
  }
  // zb = adj @ xwT.T + b_gc, split-K=2 (grid.z) -> f32 partials
  {
    dim3 g(4096 / 64, 2, 2);
    k_mgemm<64, 64><<<g, 256, 0, stream>>>(ae_adj, 4096, xwTh, 4096, b_gc,
                                           zpart, 128, 4096, 128, 4096, 0, 2048);
  }
  k_zcomb<<<512, 256, 0, stream>>>(zpart, zh, 4096 * 128 / 4);
  k_loss_mfma<<<dim3(32, 32), 256, 0, stream>>>(zh, ae_adj, lacc);
  k_final<<<1, 1, 0, stream>>>(lacc, out + (size_t)NB * 128);
}

// Round 6
// 637.483 us; speedup vs baseline: 1.2439x; 1.2439x over previous
//
#include <hip/hip_runtime.h>
#include <math.h>

// ---------------------------------------------------------------------------
// TGAT classifier. Algebraic folding (score/aggregate in input space,
// wq/wk/wv/W_lin/fc_w folded into SW/F), f16 MFMA everywhere.
// Round 6: k_score back to block-per-row (4 waves/row) with f16 LDS staging
// (12.5 KB -> 8 blocks/CU), fdot2 dots, thread-per-column aggregate;
// zb split-K=4. k_tail / k_loss_mfma retained from round 5.
// ---------------------------------------------------------------------------

typedef _Float16 h2 __attribute__((ext_vector_type(2)));
typedef _Float16 h4 __attribute__((ext_vector_type(4)));
typedef _Float16 h8 __attribute__((ext_vector_type(8)));
typedef float f4 __attribute__((ext_vector_type(4)));

// ---------------- setup fold kernels ----------------

__global__ __launch_bounds__(256) void k_prep1(
    const float* __restrict__ phase, const float* __restrict__ wq,
    float* __restrict__ te0, float* __restrict__ bq)
{
  int l = blockIdx.x, t = threadIdx.x;
  __shared__ float te[128];
  if (t < 128) te[t] = cosf(phase[t]);
  __syncthreads();
  if (l == 0 && t < 128) te0[t] = te[t];
  const float* wr = wq + ((size_t)l * 256 + t) * 256 + 128;
  float s = 0.f;
  for (int k = 0; k < 128; k++) s += wr[k] * te[k];
  bq[l * 256 + t] = s;
}

__global__ __launch_bounds__(256) void k_prep2(
    const float* __restrict__ wk, const float* __restrict__ bq, float* __restrict__ cbf)
{
  int lh = blockIdx.x, l = lh >> 1, h = lh & 1, e = threadIdx.x;
  const float* wkb = wk + (size_t)l * 65536 + (size_t)h * 128 * 256;
  const float* bqb = bq + l * 256 + h * 128;
  float s = 0.f;
  for (int d = 0; d < 128; d++) s += wkb[(size_t)d * 256 + e] * bqb[d];
  cbf[lh * 256 + e] = s;
}

__global__ __launch_bounds__(256) void k_prepM(
    const float* __restrict__ wq, const float* __restrict__ wk, float* __restrict__ Mb)
{
  int lh = blockIdx.y, l = lh >> 1, h = lh & 1;
  int idx = blockIdx.x * 256 + threadIdx.x;   // < 256*128
  int e = idx >> 7, s = idx & 127;
  const float* wkb = wk + (size_t)l * 65536 + (size_t)h * 128 * 256;
  const float* wqb = wq + (size_t)l * 65536 + (size_t)h * 128 * 256;
  float acc = 0.f;
  for (int d = 0; d < 128; d++) acc += wkb[(size_t)d * 256 + e] * wqb[(size_t)d * 256 + s];
  Mb[(size_t)lh * 32768 + idx] = acc;
}

__global__ __launch_bounds__(256) void k_build_SW(
    _Float16* __restrict__ SWa, float* __restrict__ cba,
    const float* __restrict__ Mb, const float* __restrict__ cbf,
    const float* __restrict__ Wlin, const float* __restrict__ blin)
{
  int ci = blockIdx.y;
  int lyr = (ci == 2) ? 1 : 0;
  int ul  = (ci == 0) ? 1 : 0;
  const float* M2 = Mb + (size_t)lyr * 2 * 32768;
  const float* c2 = cbf + (size_t)lyr * 512;
  _Float16* SW = SWa + (size_t)ci * 520 * 128;
  float* cb = cba + (size_t)ci * 520;
  int idx = blockIdx.x * 256 + threadIdx.x;
  if (idx >= 520 * 128) return;
  int urow = idx / 128, s = idx % 128;
  int h = urow / 260, u = urow % 260;
  const float* M = M2 + (size_t)h * 32768;
  const float* c = c2 + h * 256;
  float val = 0.f, cbv = 0.f;
  if (u < 128) {
    if (ul) {
      for (int cc = 0; cc < 128; cc++) {
        float w = Wlin[cc * 128 + u];
        val += w * M[cc * 128 + s];
        cbv += w * c[cc];
      }
    } else { val = M[u * 128 + s]; cbv = c[u]; }
  } else if (u < 256) {
    val = M[u * 128 + s]; cbv = c[u];
  } else if (u == 256) {
    if (ul) {
      for (int cc = 0; cc < 128; cc++) {
        float w = blin[cc];
        val += w * M[cc * 128 + s];
        cbv += w * c[cc];
      }
    }
  }
  SW[(size_t)urow * 128 + s] = (_Float16)val;
  if (s == 0) cb[urow] = cbv;
}

__global__ __launch_bounds__(256) void k_build_OW(
    float* __restrict__ OWa, const float* __restrict__ wv,
    const float* __restrict__ Wlin, const float* __restrict__ blin)
{
  int ci = blockIdx.y;
  int lyr = (ci == 2) ? 1 : 0;
  int ul  = (ci == 0) ? 1 : 0;
  float* OW = OWa + (size_t)ci * 2 * 128 * 260;
  const float* wvl = wv + (size_t)lyr * 65536;
  int idx = blockIdx.x * 256 + threadIdx.x;
  if (idx >= 2 * 128 * 260) return;
  int u = idx % 260; int d = (idx / 260) % 128; int h = idx / (260 * 128);
  const float* wr = wvl + (size_t)(h * 128 + d) * 256;
  float val = 0.f;
  if (u < 128) {
    if (ul) { for (int cc = 0; cc < 128; cc++) val += wr[cc] * Wlin[cc * 128 + u]; }
    else val = wr[u];
  } else if (u < 256) {
    val = wr[u];
  } else if (u == 256) {
    if (ul) { for (int cc = 0; cc < 128; cc++) val += wr[cc] * blin[cc]; }
  }
  OW[idx] = val;
}

__global__ __launch_bounds__(256) void k_build_F(
    _Float16* __restrict__ Fa, const float* __restrict__ fcw, const float* __restrict__ OWa)
{
  int ci = blockIdx.y >> 1, h = blockIdx.y & 1;
  int lyr = (ci == 2) ? 1 : 0;
  int idx = blockIdx.x * 256 + threadIdx.x;   // < 256*260
  int p = idx / 260, u = idx % 260;
  const float* fw = fcw + (size_t)lyr * 65536 + (size_t)p * 256 + h * 128;
  const float* ow = OWa + (size_t)ci * 2 * 128 * 260 + (size_t)h * 128 * 260;
  float s = 0.f;
  for (int d = 0; d < 128; d++) s += fw[d] * ow[(size_t)d * 260 + u];
  Fa[(size_t)ci * 256 * 520 + (size_t)p * 520 + h * 260 + u] = (_Float16)s;
}

// one launch: W_lin,m1w,m2w f2h + W_gc transpose-f2h + lacc zero
__global__ __launch_bounds__(256) void k_convert(
    const float* __restrict__ Wlin, const float* __restrict__ m1w,
    const float* __restrict__ m2w, const float* __restrict__ Wgc,
    _Float16* __restrict__ Wlinh, _Float16* __restrict__ m1wh,
    _Float16* __restrict__ m2wh, _Float16* __restrict__ WgcTh,
    float* __restrict__ lacc)
{
  int idx = blockIdx.x * 256 + threadIdx.x;
  if (idx == 0) lacc[0] = 0.f;
  int i = idx;
  if (i < 16384) { Wlinh[i] = (_Float16)Wlin[i]; return; }
  i -= 16384;
  if (i < 98304) { m1wh[i] = (_Float16)m1w[i]; return; }
  i -= 98304;
  if (i < 32768) { m2wh[i] = (_Float16)m2w[i]; return; }
  i -= 32768;
  if (i < 16384) {
    int c = i >> 7, r = i & 127;
    WgcTh[i] = (_Float16)Wgc[(size_t)r * 128 + c];
  }
}

// ---------------- generic f16 MFMA GEMM: C[M,N] = A[M,K](f32) @ Bh[N,K].T
// (+bias f32). cmode: 0 f32 store (+split-K partials via blockIdx.z),
// 1 f16 store, 2 f16 transposed store (C[N][ldc]). M % BM == 0.

template<int BM, int BN>
__global__ __launch_bounds__(256) void k_mgemm(
    const float* __restrict__ A, int lda,
    const _Float16* __restrict__ Bh, int ldb,
    const float* __restrict__ bias,
    float* __restrict__ C, int ldc,
    int M, int N, int K, int cmode, int klen)
{
  constexpr int BK = 64;
  constexpr int LDS = BK + 8;
  __shared__ _Float16 As[BM][LDS];
  __shared__ _Float16 Bs[BN][LDS];
  constexpr int FM = BM / 32;
  constexpr int FN = BN / 32;
  int tid = threadIdx.x;
  int wv = tid >> 6, lane = tid & 63;
  int wm = wv >> 1, wn = wv & 1;
  int row0 = blockIdx.x * BM, col0 = blockIdx.y * BN;
  int m0 = wm * (BM / 2), n0 = wn * (BN / 2);
  int lr = lane & 15, lk = lane >> 4;
  int z = blockIdx.z;
  int kbeg = z * klen;
  int kend = kbeg + klen; if (kend > K) kend = K;

  f4 acc[FM][FN];
#pragma unroll
  for (int i = 0; i < FM; i++)
#pragma unroll
    for (int j = 0; j < FN; j++) acc[i][j] = (f4)0.f;

  constexpr int TPRA = 256 / BM;
  constexpr int F4A = (BK / TPRA) / 4;
  int arow = tid / TPRA;
  int acol = (tid % TPRA) * (BK / TPRA);
  constexpr int TPRB = 256 / BN;
  constexpr int F4B = (BK / TPRB) / 4;
  int brow = tid / TPRB;
  int bcol = (tid % TPRB) * (BK / TPRB);
  int gar = row0 + arow;
  int gbr = col0 + brow;
  bool bvalid = gbr < N;

  for (int k0 = kbeg; k0 < kend; k0 += BK) {
    __syncthreads();
#pragma unroll
    for (int j = 0; j < F4A; j++) {
      int ka = k0 + acol + j * 4;
      f4 v = (f4)0.f;
      if (ka < K) v = *(const f4*)&A[(size_t)gar * lda + ka];
      h4 hv = { (_Float16)v.x, (_Float16)v.y, (_Float16)v.z, (_Float16)v.w };
      *(h4*)&As[arow][acol + j * 4] = hv;
    }
#pragma unroll
    for (int j = 0; j < F4B; j++) {
      int ka = k0 + bcol + j * 4;
      h4 hv = (h4)(_Float16)0.f;
      if (bvalid && ka < K) hv = *(const h4*)&Bh[(size_t)gbr * ldb + ka];
      *(h4*)&Bs[brow][bcol + j * 4] = hv;
    }
    __syncthreads();
#pragma unroll
    for (int kk = 0; kk < 2; kk++) {
      h8 af[FM], bf[FN];
#pragma unroll
      for (int i = 0; i < FM; i++)
        af[i] = *(h8*)&As[m0 + i * 16 + lr][kk * 32 + lk * 8];
#pragma unroll
      for (int j = 0; j < FN; j++)
        bf[j] = *(h8*)&Bs[n0 + j * 16 + lr][kk * 32 + lk * 8];
#pragma unroll
      for (int i = 0; i < FM; i++)
#pragma unroll
        for (int j = 0; j < FN; j++)
          acc[i][j] = __builtin_amdgcn_mfma_f32_16x16x32_f16(af[i], bf[j], acc[i][j], 0, 0, 0);
    }
  }
  float* Cz = C + (size_t)z * M * ldc;   // split-K partial offset (cmode 0)
#pragma unroll
  for (int j = 0; j < FN; j++) {
    int c = col0 + n0 + j * 16 + lr;
    if (c >= N) continue;
    float bz = (bias && z == 0) ? bias[c] : 0.f;
#pragma unroll
    for (int i = 0; i < FM; i++) {
      int rbase = row0 + m0 + i * 16 + lk * 4;
#pragma unroll
      for (int r = 0; r < 4; r++) {
        int rr = rbase + r;
        float v = acc[i][j][r] + bz;
        if (cmode == 0) Cz[(size_t)rr * ldc + c] = v;
        else if (cmode == 1) ((_Float16*)C)[(size_t)rr * ldc + c] = (_Float16)v;
        else ((_Float16*)C)[(size_t)c * ldc + rr] = (_Float16)v;
      }
    }
  }
}

// sum 4 split-K partials -> f16
__global__ __launch_bounds__(256) void k_zcomb(
    const float* __restrict__ zp, _Float16* __restrict__ zh, int n4)
{
  int i = blockIdx.x * 256 + threadIdx.x;
  if (i >= n4) return;
  f4 a = ((const f4*)zp)[i];
  f4 b = ((const f4*)zp)[n4 + i];
  f4 c = ((const f4*)zp)[2 * n4 + i];
  f4 d = ((const f4*)zp)[3 * n4 + i];
  h4 o = { (_Float16)(a.x + b.x + c.x + d.x), (_Float16)(a.y + b.y + c.y + d.y),
           (_Float16)(a.z + b.z + c.z + d.z), (_Float16)(a.w + b.w + c.w + d.w) };
  ((h4*)zh)[i] = o;
}

// ---------------- score/softmax/aggregate: block per row, f16 LDS -----------
// 4 waves cooperate on one row; LDS ~12.5 KB -> 8 blocks/CU.

__global__ __launch_bounds__(256, 8) void k_score(
    _Float16* __restrict__ UY,
    const float* __restrict__ feat,   // [rows][20][128] f32
    const float* __restrict__ tsrc,
    const float* __restrict__ tngh,
    const int*   __restrict__ idx,
    const float* __restrict__ freq, const float* __restrict__ phase,
    int rows)
{
  __shared__ _Float16 fsh[20][136];
  __shared__ _Float16 tesh[20][136];
  __shared__ _Float16 ush[544];     // head h at h*264 (u<260); sb at h*264+256
  __shared__ float ssh[2][20];
  __shared__ float ash[2][20];
  __shared__ float dtsh[20];
  __shared__ int   msh[20];
  int row = blockIdx.x;
  int tid = threadIdx.x;

  if (tid < 20) {
    dtsh[tid] = tsrc[row] - tngh[(size_t)row * 20 + tid];
    msh[tid] = (idx[(size_t)row * 20 + tid] == 0);
  }
  if (tid < 130) {
    h4 v = *(const h4*)&UY[(size_t)row * 520 + tid * 4];
    int p4 = (tid < 65) ? tid : tid + 1;
    *(h4*)&ush[p4 * 4] = v;
  }
  const float4* fg = (const float4*)(feat + (size_t)row * 2560);
  for (int i = tid; i < 640; i += 256) {
    int j = i >> 5, c4 = i & 31;
    float4 v = fg[i];
    h4 hv = { (_Float16)v.x, (_Float16)v.y, (_Float16)v.z, (_Float16)v.w };
    *(h4*)&fsh[j][c4 * 4] = hv;
  }
  __syncthreads();
  for (int i = tid; i < 2560; i += 256) {
    int j = i >> 7, t = i & 127;
    tesh[j][t] = (_Float16)__cosf(dtsh[j] * freq[t] + phase[t]);
  }
  __syncthreads();

  // dots: 16 groups of 16 threads; 40 tasks (2 heads x 20 neighbors)
  int g = tid >> 4, li = tid & 15;
#pragma unroll
  for (int it = 0; it < 3; it++) {
    int t = it * 16 + g;
    int valid = (t < 40);
    int h = valid ? (t / 20) : 0;
    int j = valid ? (t % 20) : 0;
    float part = 0.f;
    if (valid) {
      const _Float16* xp = (li < 8) ? &fsh[j][li * 16] : &tesh[j][(li - 8) * 16];
      const _Float16* up = &ush[h * 264 + li * 16];
#pragma unroll
      for (int e = 0; e < 8; e++) {
        h2 a = *(const h2*)(xp + e * 2);
        h2 b = *(const h2*)(up + e * 2);
        part = __builtin_amdgcn_fdot2(a, b, part, false);
      }
    }
    for (int m = 8; m; m >>= 1) part += __shfl_xor(part, m, 16);
    if (valid && li == 0) ssh[h][j] = part + (float)ush[h * 264 + 256];
  }
  __syncthreads();

  // softmax: wave 0, half-wave per head
  if (tid < 64) {
    int head = tid >> 5, l2 = tid & 31;
    const float scale = 0.08838834764831845f; // 1/sqrt(128)
    float s = (l2 < 20) ? (msh[l2] ? -1e10f : ssh[head][l2] * scale) : -3.0e38f;
    float mx = s;
    for (int m = 16; m; m >>= 1) mx = fmaxf(mx, __shfl_xor(mx, m, 32));
    float e = (l2 < 20) ? __expf(s - mx) : 0.f;
    float sum = e;
    for (int m = 16; m; m >>= 1) sum += __shfl_xor(sum, m, 32);
    if (l2 < 20) ash[head][l2] = e / sum;
  }
  __syncthreads();

  // aggregate: thread owns position p (0..255) for both heads
  {
    int p = tid;
    const _Float16* colp = (p < 128) ? &fsh[0][p] : &tesh[0][p - 128];
    float a0 = 0.f, a1 = 0.f;
#pragma unroll 5
    for (int j = 0; j < 20; j++) {
      float x = (float)colp[j * 136];
      a0 += ash[0][j] * x;
      a1 += ash[1][j] * x;
    }
    UY[(size_t)row * 520 + p] = (_Float16)a0;
    UY[(size_t)row * 520 + 260 + p] = (_Float16)a1;
  }
  if (tid < 8) {
    int p = (tid < 4) ? (256 + tid) : (512 + tid);   // 256..259, 516..519
    _Float16 v = (_Float16)((tid == 0 || tid == 4) ? 1.f : 0.f);
    UY[(size_t)row * 520 + p] = v;
  }
}

// ---------------- fused tail: P-GEMM + residual + LN + MergeLayer -----------
// per block: 64 rows. P = U@F.T (+fcb+q, LN) -> LDS f16; H = relu([P|src]@m1w.T
// + m1b) -> LDS; out = H@m2w.T + m2b (f32). B-frags direct from L2.

__global__ __launch_bounds__(256) void k_tail(
    const _Float16* __restrict__ U,   // [rows][520]
    const _Float16* __restrict__ F,   // [256][520]
    const float* __restrict__ fcb,
    const float* __restrict__ srcv,   // [rows][128] f32
    const float* __restrict__ te0,
    const float* __restrict__ lng, const float* __restrict__ lnb,
    const _Float16* __restrict__ m1w, // [128][384]
    const float* __restrict__ m1b,
    const _Float16* __restrict__ m2w, // [128][128]
    const float* __restrict__ m2b,
    float* __restrict__ outp, int rows)
{
  __shared__ _Float16 Ps[64][264];
  __shared__ _Float16 Ss[64][136];    // src f16; reused as H after m1
  __shared__ float redS[64][4], redQ[64][4];
  __shared__ float mrow[64], rrow[64];
  int tid = threadIdx.x;
  int wv = tid >> 6, lane = tid & 63;
  int lr = lane & 15, lk = lane >> 4;
  int row0 = blockIdx.x * 64;
  int n0 = wv * 64;

  // stage src f32 -> f16 (m1 phase, k=256..383)
  {
    const float4* sg = (const float4*)(srcv + (size_t)row0 * 128);
    for (int i = tid; i < 2048; i += 256) {
      int rr = i >> 5, c4 = i & 31;
      float4 v = sg[i];
      h4 hv = { (_Float16)v.x, (_Float16)v.y, (_Float16)v.z, (_Float16)v.w };
      *(h4*)&Ss[rr][c4 * 4] = hv;
    }
  }

  // phase 1: P-GEMM (64x256, K=520), fragments direct from global (L2)
  f4 acc[4][4];
#pragma unroll
  for (int i = 0; i < 4; i++)
#pragma unroll
    for (int j = 0; j < 4; j++) acc[i][j] = (f4)0.f;
  for (int kt = 0; kt < 17; kt++) {
    int kb = kt * 32 + lk * 8;
    bool ok = (kb + 8 <= 520);
    h8 af[4], bf[4];
#pragma unroll
    for (int i = 0; i < 4; i++)
      af[i] = ok ? *(const h8*)&U[(size_t)(row0 + i * 16 + lr) * 520 + kb]
                 : (h8)(_Float16)0.f;
#pragma unroll
    for (int j = 0; j < 4; j++)
      bf[j] = ok ? *(const h8*)&F[(size_t)(n0 + j * 16 + lr) * 520 + kb]
                 : (h8)(_Float16)0.f;
#pragma unroll
    for (int i = 0; i < 4; i++)
#pragma unroll
      for (int j = 0; j < 4; j++)
        acc[i][j] = __builtin_amdgcn_mfma_f32_16x16x32_f16(af[i], bf[j], acc[i][j], 0, 0, 0);
  }

  // epilogue: + fcb + q, row-reduce for LN
#pragma unroll
  for (int i = 0; i < 4; i++) {
#pragma unroll
    for (int r = 0; r < 4; r++) {
      int row_l = i * 16 + lk * 4 + r;
      float rs = 0.f, rq = 0.f;
#pragma unroll
      for (int j = 0; j < 4; j++) {
        int c = n0 + j * 16 + lr;
        float q = (c < 128) ? srcv[(size_t)(row0 + row_l) * 128 + c] : te0[c - 128];
        float v = acc[i][j][r] + fcb[c] + q;
        acc[i][j][r] = v;
        rs += v; rq += v * v;
      }
      for (int m = 8; m; m >>= 1) {
        rs += __shfl_xor(rs, m, 16);
        rq += __shfl_xor(rq, m, 16);
      }
      if (lr == 0) { redS[row_l][wv] = rs; redQ[row_l][wv] = rq; }
    }
  }
  __syncthreads();
  if (tid < 64) {
    float s4 = redS[tid][0] + redS[tid][1] + redS[tid][2] + redS[tid][3];
    float q4 = redQ[tid][0] + redQ[tid][1] + redQ[tid][2] + redQ[tid][3];
    float mean = s4 * (1.0f / 256.0f);
    float var = q4 * (1.0f / 256.0f) - mean * mean;
    mrow[tid] = mean;
    rrow[tid] = rsqrtf(var + 1e-5f);
  }
  __syncthreads();
#pragma unroll
  for (int i = 0; i < 4; i++) {
#pragma unroll
    for (int r = 0; r < 4; r++) {
      int row_l = i * 16 + lk * 4 + r;
      float mean = mrow[row_l], rstd = rrow[row_l];
#pragma unroll
      for (int j = 0; j < 4; j++) {
        int c = n0 + j * 16 + lr;
        Ps[row_l][c] = (_Float16)((acc[i][j][r] - mean) * rstd * lng[c] + lnb[c]);
      }
    }
  }
  __syncthreads();

  // phase 2: m1 (64x128, K=384: [Ps|Ss]); B-frags from global m1w
  int wm = wv >> 1, wn = wv & 1;
  f4 a2[2][4];
#pragma unroll
  for (int i = 0; i < 2; i++)
#pragma unroll
    for (int j = 0; j < 4; j++) a2[i][j] = (f4)0.f;
  for (int kk = 0; kk < 12; kk++) {
    int kb = kk * 32 + lk * 8;
    h8 af[2], bf[4];
#pragma unroll
    for (int i = 0; i < 2; i++) {
      int rl = wm * 32 + i * 16 + lr;
      af[i] = (kb < 256) ? *(const h8*)&Ps[rl][kb] : *(const h8*)&Ss[rl][kb - 256];
    }
#pragma unroll
    for (int j = 0; j < 4; j++)
      bf[j] = *(const h8*)&m1w[(size_t)(wn * 64 + j * 16 + lr) * 384 + kb];
#pragma unroll
    for (int i = 0; i < 2; i++)
#pragma unroll
      for (int j = 0; j < 4; j++)
        a2[i][j] = __builtin_amdgcn_mfma_f32_16x16x32_f16(af[i], bf[j], a2[i][j], 0, 0, 0);
  }
  __syncthreads();   // everyone done reading Ss before H overwrites it
#pragma unroll
  for (int i = 0; i < 2; i++) {
#pragma unroll
    for (int j = 0; j < 4; j++) {
      int c = wn * 64 + j * 16 + lr;
      float bz = m1b[c];
#pragma unroll
      for (int r = 0; r < 4; r++) {
        float v = a2[i][j][r] + bz;
        if (v < 0.f) v = 0.f;
        Ss[wm * 32 + i * 16 + lk * 4 + r][c] = (_Float16)v;   // H
      }
    }
  }
  __syncthreads();

  // phase 3: m2 (64x128, K=128); B-frags from global m2w
  f4 a3[2][4];
#pragma unroll
  for (int i = 0; i < 2; i++)
#pragma unroll
    for (int j = 0; j < 4; j++) a3[i][j] = (f4)0.f;
#pragma unroll
  for (int kk = 0; kk < 4; kk++) {
    int kb = kk * 32 + lk * 8;
    h8 af[2], bf[4];
#pragma unroll
    for (int i = 0; i < 2; i++)
      af[i] = *(const h8*)&Ss[wm * 32 + i * 16 + lr][kb];
#pragma unroll
    for (int j = 0; j < 4; j++)
      bf[j] = *(const h8*)&m2w[(size_t)(wn * 64 + j * 16 + lr) * 128 + kb];
#pragma unroll
    for (int i = 0; i < 2; i++)
#pragma unroll
      for (int j = 0; j < 4; j++)
        a3[i][j] = __builtin_amdgcn_mfma_f32_16x16x32_f16(af[i], bf[j], a3[i][j], 0, 0, 0);
  }
#pragma unroll
  for (int j = 0; j < 4; j++) {
    int c = wn * 64 + j * 16 + lr;
    float bz = m2b[c];
#pragma unroll
    for (int i = 0; i < 2; i++) {
#pragma unroll
      for (int r = 0; r < 4; r++) {
        int rl = wm * 32 + i * 16 + lk * 4 + r;
        outp[(size_t)(row0 + rl) * 128 + c] = a3[i][j][r] + bz;
      }
    }
  }
}

// ---------------- fused MFMA autoencoder loss --------------------------------

__global__ __launch_bounds__(256) void k_loss_mfma(
    const _Float16* __restrict__ z, const float* __restrict__ adj,
    float* __restrict__ acc)
{
  int tid = threadIdx.x;
  int wv = tid >> 6, lane = tid & 63;
  int wm = wv >> 1, wn = wv & 1;
  int lr = lane & 15, lk = lane >> 4;
  int row0 = blockIdx.x * 128 + wm * 64;
  int col0 = blockIdx.y * 128 + wn * 64;

  f4 accf[4][4];
#pragma unroll
  for (int i = 0; i < 4; i++)
#pragma unroll
    for (int j = 0; j < 4; j++) accf[i][j] = (f4)0.f;

#pragma unroll
  for (int kk = 0; kk < 4; kk++) {
    int ko = kk * 32 + lk * 8;
    h8 af[4], bf[4];
#pragma unroll
    for (int i = 0; i < 4; i++)
      af[i] = *(const h8*)&z[(size_t)(row0 + i * 16 + lr) * 128 + ko];
#pragma unroll
    for (int j = 0; j < 4; j++)
      bf[j] = *(const h8*)&z[(size_t)(col0 + j * 16 + lr) * 128 + ko];
#pragma unroll
    for (int i = 0; i < 4; i++)
#pragma unroll
      for (int j = 0; j < 4; j++)
        accf[i][j] = __builtin_amdgcn_mfma_f32_16x16x32_f16(af[i], bf[j], accf[i][j], 0, 0, 0);
  }

  float lsum = 0.f;
#pragma unroll
  for (int i = 0; i < 4; i++) {
    int rbase = row0 + i * 16 + lk * 4;
#pragma unroll
    for (int r = 0; r < 4; r++) {
      const float* arow = adj + (size_t)(rbase + r) * 4096;
#pragma unroll
      for (int j = 0; j < 4; j++) {
        float x = accf[i][j][r];
        float s = 1.0f / (1.0f + __expf(-x));
        float d = arow[col0 + j * 16 + lr] - s;
        lsum += d * d;
      }
    }
  }
  for (int m = 32; m; m >>= 1) lsum += __shfl_xor(lsum, m, 64);
  if (lane == 0) atomicAdd(acc, lsum);
}

__global__ void k_final(const float* acc, float* out) {
  out[0] = acc[0] * (1.0f / (4096.0f * 4096.0f));
}

// ---------------------------------------------------------------------------

extern "C" void kernel_launch(void* const* d_in, const int* in_sizes, int n_in,
                              void* d_out, int out_size, void* d_ws, size_t ws_size,
                              hipStream_t stream) {
  const float* src_feat  = (const float*)d_in[0];
  const float* src_t     = (const float*)d_in[1];
  const int*   ngh1_idx  = (const int*)d_in[2];
  const float* ngh1_t    = (const float*)d_in[3];
  const float* ngh1_feat = (const float*)d_in[4];
  const int*   ngh2_idx  = (const int*)d_in[5];
  const float* ngh2_t    = (const float*)d_in[6];
  const float* ngh2_feat = (const float*)d_in[7];
  const float* ae_x      = (const float*)d_in[8];
  const float* ae_adj    = (const float*)d_in[9];
  const float* W_lin     = (const float*)d_in[10];
  const float* b_lin     = (const float*)d_in[11];
  const float* freq      = (const float*)d_in[12];
  const float* phase     = (const float*)d_in[13];
  const float* wq        = (const float*)d_in[14];
  const float* wk        = (const float*)d_in[15];
  const float* wv        = (const float*)d_in[16];
  const float* fcw       = (const float*)d_in[17];
  const float* fcb       = (const float*)d_in[18];
  const float* lng       = (const float*)d_in[19];
  const float* lnb       = (const float*)d_in[20];
  const float* m1w       = (const float*)d_in[21];
  const float* m1b       = (const float*)d_in[22];
  const float* m2w       = (const float*)d_in[23];
  const float* m2b       = (const float*)d_in[24];
  const float* W_gc      = (const float*)d_in[25];
  const float* b_gc      = (const float*)d_in[26];
  float* out = (float*)d_out;

  const int NB = 2048, NA = 40960;

  char* w = (char*)d_ws;
  size_t off = 0;
  auto alloc = [&](size_t bytes) -> void* {
    void* p = (void*)(w + off);
    off += (bytes + 255) & ~(size_t)255;
    return p;
  };
  float* te0    = (float*)alloc(128 * 4);
  float* linS   = (float*)alloc((size_t)NB * 128 * 4);
  float* lin1   = (float*)alloc((size_t)NA * 128 * 4);
  float* src_l1 = (float*)alloc((size_t)NB * 128 * 4);
  float* ngh_l1 = (float*)alloc((size_t)NA * 128 * 4);
  float* bq     = (float*)alloc(2 * 256 * 4);
  float* Mb     = (float*)alloc((size_t)2 * 2 * 256 * 128 * 4);
  float* cbf    = (float*)alloc(2 * 2 * 256 * 4);
  _Float16* SWh = (_Float16*)alloc((size_t)3 * 520 * 128 * 2);
  float* cbU    = (float*)alloc(3 * 520 * 4);
  float* OW     = (float*)alloc((size_t)3 * 2 * 128 * 260 * 4);
  _Float16* Fh  = (_Float16*)alloc((size_t)3 * 256 * 520 * 2);
  _Float16* Wlinh = (_Float16*)alloc(16384 * 2);
  _Float16* m1wh  = (_Float16*)alloc((size_t)2 * 128 * 384 * 2);
  _Float16* m2wh  = (_Float16*)alloc((size_t)2 * 128 * 128 * 2);
  _Float16* WgcTh = (_Float16*)alloc(16384 * 2);
  _Float16* xwTh  = (_Float16*)alloc((size_t)4096 * 128 * 2);
  float* zpart    = (float*)alloc((size_t)4 * 4096 * 128 * 4);
  _Float16* zh    = (_Float16*)alloc((size_t)4096 * 128 * 2);
  float* lacc   = (float*)alloc(256);
  size_t fixed = off;

  size_t avail = (ws_size > fixed) ? (ws_size - fixed) : 0;
  long rows_c = (long)(avail / 1100);   // 520*2 B/row + margin
  if (rows_c > NA) rows_c = NA;
  rows_c &= ~127L;
  if (rows_c < 2048) rows_c = 2048;
  _Float16* Ubuf = (_Float16*)alloc((size_t)rows_c * 520 * 2);

  auto gemm128 = [&](const float* A, int lda, const _Float16* Bm, int ldb,
                     const float* bias, float* Cm, int ldc,
                     int M, int N, int Kd, int cmode) {
    dim3 g(M / 128, (N + 127) / 128);
    k_mgemm<128, 128><<<g, 256, 0, stream>>>(A, lda, Bm, ldb, bias, Cm, ldc,
                                             M, N, Kd, cmode, Kd);
  };

  // ---- folded weights (7 launches) ----
  k_prep1<<<2, 256, 0, stream>>>(phase, wq, te0, bq);
  k_prep2<<<4, 256, 0, stream>>>(wk, bq, cbf);
  k_prepM<<<dim3(128, 4), 256, 0, stream>>>(wq, wk, Mb);
  k_build_SW<<<dim3(260, 3), 256, 0, stream>>>(SWh, cbU, Mb, cbf, W_lin, b_lin);
  k_build_OW<<<dim3(260, 3), 256, 0, stream>>>(OW, wv, W_lin, b_lin);
  k_build_F<<<dim3(260, 6), 256, 0, stream>>>(Fh, fcw, OW);
  k_convert<<<640, 256, 0, stream>>>(W_lin, m1w, m2w, W_gc, Wlinh, m1wh, m2wh,
                                     WgcTh, lacc);

  // ---- feature linear layers ----
  gemm128(src_feat, 128, Wlinh, 128, b_lin, linS, 128, NB, 128, 128, 0);
  gemm128(ngh1_feat, 128, Wlinh, 128, b_lin, lin1, 128, NA, 128, 128, 0);

  // ---- attention calls: U-GEMM -> score -> tail ----
  auto attn_call = [&](int ci, long rows_total, const float* srcvec,
                       const float* featp, const float* tsrcp, const float* tnghp,
                       const int* idxp, int l, float* outp) {
    for (long r0 = 0; r0 < rows_total; r0 += rows_c) {
      long rem = rows_total - r0;
      int rows = (int)(rem < rows_c ? rem : rows_c);
      gemm128(srcvec + r0 * 128, 128, SWh + (size_t)ci * 520 * 128, 128,
              cbU + ci * 520, (float*)Ubuf, 520, rows, 520, 128, 1);
      k_score<<<rows, 256, 0, stream>>>(Ubuf, featp + r0 * 2560, tsrcp + r0,
                                        tnghp + r0 * 20, idxp + r0 * 20,
                                        freq, phase, rows);
      k_tail<<<rows / 64, 256, 0, stream>>>(
          Ubuf, Fh + (size_t)ci * 256 * 520, fcb + l * 256, srcvec + r0 * 128,
          te0, lng + l * 256, lnb + l * 256,
          m1wh + (size_t)l * 128 * 384, m1b + l * 128,
          m2wh + (size_t)l * 128 * 128, m2b + l * 128, outp + r0 * 128, rows);
    }
  };
  attn_call(0, NA, lin1, ngh2_feat, ngh1_t, ngh2_t, ngh2_idx, 0, ngh_l1);
  attn_call(1, NB, linS, lin1, src_t, ngh1_t, ngh1_idx, 0, src_l1);
  attn_call(2, NB, src_l1, ngh_l1, src_t, ngh1_t, ngh1_idx, 1, out);

  // ---- autoencoder loss ----
  // xw^T directly via transposed f16 store (cmode 2, ldc = 4096)
  {
    dim3 g(4096 / 128, 1);
    k_mgemm<128, 128><<<g, 256, 0, stream>>>(ae_x, 128, WgcTh, 128, nullptr,
                                             (float*)xwTh, 4096, 4096, 128, 128, 2, 128);
  }
  // zb = adj @ xwT.T + b_gc, split-K=4 (grid.z) -> f32 partials
  {
    dim3 g(4096 / 64, 2, 4);
    k_mgemm<64, 64><<<g, 256, 0, stream>>>(ae_adj, 4096, xwTh, 4096, b_gc,
                                           zpart, 128, 4096, 128, 4096, 0, 1024);
  }
  k_zcomb<<<512, 256, 0, stream>>>(zpart, zh, 4096 * 128 / 4);
  k_loss_mfma<<<dim3(32, 32), 256, 0, stream>>>(zh, ae_adj, lacc);
  k_final<<<1, 1, 0, stream>>>(lacc, out + (size_t)NB * 128);
}

// Round 7
// 502.145 us; speedup vs baseline: 1.5792x; 1.2695x over previous
//
#include <hip/hip_runtime.h>
#include <math.h>

// ---------------------------------------------------------------------------
// TGAT classifier. Algebraic folding (score/aggregate in input space,
// wq/wk/wv/W_lin/fc_w folded into SW/F), f16 MFMA everywhere.
// Round 7: horizontal fusion -> 9 launches total.
//   L1 k_prep_a   {cbf(te->bq->cbf per-block), prepM, build_OW, converts}
//   L2 k_prep_b   {build_SW, build_F}
//   L3 gemm_multi {linS, lin1, xwT}
//   L4 gemm_multi {U-A, U-B, zb split-K=8}
//   L5 score_multi{score-A 40960, score-B 2048, zcomb}
//   L6 tail_loss  {tail-A, tail-B, loss-MFMA}
//   L7 gemm_multi {U-C, final-loss-write}
//   L8 score_multi{score-C}
//   L9 tail_loss  {tail-C}
// ---------------------------------------------------------------------------

typedef _Float16 h2 __attribute__((ext_vector_type(2)));
typedef _Float16 h4 __attribute__((ext_vector_type(4)));
typedef _Float16 h8 __attribute__((ext_vector_type(8)));
typedef float f4 __attribute__((ext_vector_type(4)));

// ============================ L1: independent prep ==========================

__global__ __launch_bounds__(256) void k_prep_a(
    const float* __restrict__ phase, const float* __restrict__ wq,
    const float* __restrict__ wk, const float* __restrict__ wvw,
    const float* __restrict__ Wlin, const float* __restrict__ blin,
    const float* __restrict__ m1w, const float* __restrict__ m2w,
    const float* __restrict__ Wgc,
    float* __restrict__ te0, float* __restrict__ cbf, float* __restrict__ Mb,
    float* __restrict__ OWa,
    _Float16* __restrict__ Wlinh, _Float16* __restrict__ m1wh,
    _Float16* __restrict__ m2wh, _Float16* __restrict__ WgcTh,
    float* __restrict__ lacc)
{
  __shared__ float te[128];
  __shared__ float bqv[128];
  int b = blockIdx.x, tid = threadIdx.x;

  if (b < 4) {
    // cbf for (l,h): te -> bq slice -> cbf, all block-local
    int l = b >> 1, h = b & 1;
    if (tid < 128) {
      te[tid] = cosf(phase[tid]);
      if (b == 0) te0[tid] = te[tid];
    }
    __syncthreads();
    if (tid < 128) {
      const float* wr = wq + ((size_t)(l * 256 + h * 128 + tid)) * 256 + 128;
      float s = 0.f;
      for (int k = 0; k < 128; k++) s += wr[k] * te[k];
      bqv[tid] = s;
    }
    __syncthreads();
    {
      const float* wkb = wk + (size_t)l * 65536 + (size_t)h * 32768;
      float s = 0.f;
      for (int d = 0; d < 128; d++) s += wkb[(size_t)d * 256 + tid] * bqv[d];
      cbf[(l * 2 + h) * 256 + tid] = s;
    }
    return;
  }
  b -= 4;
  if (b < 512) {   // prepM: Mb[lh][e][s]
    int lh = b >> 7, bx = b & 127;
    int l = lh >> 1, h = lh & 1;
    int idx = bx * 256 + tid;
    int e = idx >> 7, s = idx & 127;
    const float* wkb = wk + (size_t)l * 65536 + (size_t)h * 32768;
    const float* wqb = wq + (size_t)l * 65536 + (size_t)h * 32768;
    float acc = 0.f;
    for (int d = 0; d < 128; d++)
      acc += wkb[(size_t)d * 256 + e] * wqb[(size_t)d * 256 + s];
    Mb[(size_t)lh * 32768 + idx] = acc;
    return;
  }
  b -= 512;
  if (b < 780) {   // build_OW
    int ci = b / 260, bx = b % 260;
    int lyr = (ci == 2) ? 1 : 0;
    int ul  = (ci == 0) ? 1 : 0;
    float* OW = OWa + (size_t)ci * 2 * 128 * 260;
    const float* wvl = wvw + (size_t)lyr * 65536;
    int idx = bx * 256 + tid;
    int u = idx % 260; int d = (idx / 260) % 128; int h = idx / (260 * 128);
    const float* wr = wvl + (size_t)(h * 128 + d) * 256;
    float val = 0.f;
    if (u < 128) {
      if (ul) { for (int cc = 0; cc < 128; cc++) val += wr[cc] * Wlin[cc * 128 + u]; }
      else val = wr[u];
    } else if (u < 256) {
      val = wr[u];
    } else if (u == 256) {
      if (ul) { for (int cc = 0; cc < 128; cc++) val += wr[cc] * blin[cc]; }
    }
    OW[idx] = val;
    return;
  }
  b -= 780;
  {  // converts + lacc zero (640 blocks, 163840 elems exactly)
    int idx = b * 256 + tid;
    if (idx == 0) lacc[0] = 0.f;
    int i = idx;
    if (i < 16384) { Wlinh[i] = (_Float16)Wlin[i]; return; }
    i -= 16384;
    if (i < 98304) { m1wh[i] = (_Float16)m1w[i]; return; }
    i -= 98304;
    if (i < 32768) { m2wh[i] = (_Float16)m2w[i]; return; }
    i -= 32768;
    {
      int c = i >> 7, r = i & 127;
      WgcTh[i] = (_Float16)Wgc[(size_t)r * 128 + c];
    }
  }
}

// ============================ L2: dependent prep ============================

__global__ __launch_bounds__(256) void k_prep_b(
    const float* __restrict__ Mb, const float* __restrict__ cbf,
    const float* __restrict__ Wlin, const float* __restrict__ blin,
    const float* __restrict__ fcw, const float* __restrict__ OWa,
    _Float16* __restrict__ SWa, float* __restrict__ cba,
    _Float16* __restrict__ Fa)
{
  int b = blockIdx.x, tid = threadIdx.x;
  if (b < 780) {   // build_SW
    int ci = b / 260, bx = b % 260;
    int lyr = (ci == 2) ? 1 : 0;
    int ul  = (ci == 0) ? 1 : 0;
    const float* M2 = Mb + (size_t)lyr * 2 * 32768;
    const float* c2 = cbf + (size_t)lyr * 512;
    _Float16* SW = SWa + (size_t)ci * 520 * 128;
    float* cb = cba + (size_t)ci * 520;
    int idx = bx * 256 + tid;
    int urow = idx / 128, s = idx % 128;
    int h = urow / 260, u = urow % 260;
    const float* M = M2 + (size_t)h * 32768;
    const float* c = c2 + h * 256;
    float val = 0.f, cbv = 0.f;
    if (u < 128) {
      if (ul) {
        for (int cc = 0; cc < 128; cc++) {
          float w = Wlin[cc * 128 + u];
          val += w * M[cc * 128 + s];
          cbv += w * c[cc];
        }
      } else { val = M[u * 128 + s]; cbv = c[u]; }
    } else if (u < 256) {
      val = M[u * 128 + s]; cbv = c[u];
    } else if (u == 256) {
      if (ul) {
        for (int cc = 0; cc < 128; cc++) {
          float w = blin[cc];
          val += w * M[cc * 128 + s];
          cbv += w * c[cc];
        }
      }
    }
    SW[(size_t)urow * 128 + s] = (_Float16)val;
    if (s == 0) cb[urow] = cbv;
    return;
  }
  b -= 780;
  {  // build_F: 1560 blocks
    int yy = b / 260, bx = b % 260;
    int ci = yy >> 1, h = yy & 1;
    int lyr = (ci == 2) ? 1 : 0;
    int idx = bx * 256 + tid;
    int p = idx / 260, u = idx % 260;
    const float* fw = fcw + (size_t)lyr * 65536 + (size_t)p * 256 + h * 128;
    const float* ow = OWa + (size_t)ci * 2 * 128 * 260 + (size_t)h * 128 * 260;
    float s = 0.f;
    for (int d = 0; d < 128; d++) s += fw[d] * ow[(size_t)d * 260 + u];
    Fa[(size_t)ci * 256 * 520 + (size_t)p * 520 + h * 260 + u] = (_Float16)s;
  }
}

// ===================== multi-job f16 MFMA GEMM dispatcher ===================
// C[M,N] = A[M,K](f32) @ B[N,K].T(f16) (+bias). cmode 0: f32 store w/ split-K
// partial offset z*M*ldc; 1: f16 store; 2: f16 transposed store C[N][ldc].

struct GemmJob {
  const float* A; const _Float16* B; const float* bias; float* C;
  int lda, ldb, ldc, M, N, K, cmode, klen, gx, gy, nblk;
};

__device__ __forceinline__ void gemm128_body(int lb, const GemmJob& g) {
  __shared__ _Float16 As[128][72];
  __shared__ _Float16 Bs[128][72];
  int bx = lb % g.gx;
  int rest = lb / g.gx;
  int by = rest % g.gy;
  int z = rest / g.gy;

  int tid = threadIdx.x;
  int wv = tid >> 6, lane = tid & 63;
  int wm = wv >> 1, wn = wv & 1;
  int row0 = bx * 128, col0 = by * 128;
  int m0 = wm * 64, n0 = wn * 64;
  int lr = lane & 15, lk = lane >> 4;
  int kbeg = z * g.klen;
  int kend = kbeg + g.klen; if (kend > g.K) kend = g.K;

  f4 acc[4][4];
#pragma unroll
  for (int i = 0; i < 4; i++)
#pragma unroll
    for (int j = 0; j < 4; j++) acc[i][j] = (f4)0.f;

  int arow = tid >> 1;
  int acol = (tid & 1) * 32;
  int gar = row0 + arow;
  int gbr = col0 + arow;
  bool bvalid = gbr < g.N;

  for (int k0 = kbeg; k0 < kend; k0 += 64) {
    __syncthreads();
#pragma unroll
    for (int j = 0; j < 8; j++) {
      int ka = k0 + acol + j * 4;
      f4 v = (f4)0.f;
      if (ka < g.K) v = *(const f4*)&g.A[(size_t)gar * g.lda + ka];
      h4 hv = { (_Float16)v.x, (_Float16)v.y, (_Float16)v.z, (_Float16)v.w };
      *(h4*)&As[arow][acol + j * 4] = hv;
    }
#pragma unroll
    for (int j = 0; j < 8; j++) {
      int ka = k0 + acol + j * 4;
      h4 hv = (h4)(_Float16)0.f;
      if (bvalid && ka < g.K) hv = *(const h4*)&g.B[(size_t)gbr * g.ldb + ka];
      *(h4*)&Bs[arow][acol + j * 4] = hv;
    }
    __syncthreads();
#pragma unroll
    for (int kk = 0; kk < 2; kk++) {
      h8 af[4], bf[4];
#pragma unroll
      for (int i = 0; i < 4; i++)
        af[i] = *(h8*)&As[m0 + i * 16 + lr][kk * 32 + lk * 8];
#pragma unroll
      for (int j = 0; j < 4; j++)
        bf[j] = *(h8*)&Bs[n0 + j * 16 + lr][kk * 32 + lk * 8];
#pragma unroll
      for (int i = 0; i < 4; i++)
#pragma unroll
        for (int j = 0; j < 4; j++)
          acc[i][j] = __builtin_amdgcn_mfma_f32_16x16x32_f16(af[i], bf[j], acc[i][j], 0, 0, 0);
    }
  }
  float* Cz = g.C + (size_t)z * g.M * g.ldc;
#pragma unroll
  for (int j = 0; j < 4; j++) {
    int c = col0 + n0 + j * 16 + lr;
    if (c >= g.N) continue;
    float bz = (g.bias && z == 0) ? g.bias[c] : 0.f;
#pragma unroll
    for (int i = 0; i < 4; i++) {
      int rbase = row0 + m0 + i * 16 + lk * 4;
#pragma unroll
      for (int r = 0; r < 4; r++) {
        int rr = rbase + r;
        float v = acc[i][j][r] + bz;
        if (g.cmode == 0) Cz[(size_t)rr * g.ldc + c] = v;
        else if (g.cmode == 1) ((_Float16*)g.C)[(size_t)rr * g.ldc + c] = (_Float16)v;
        else ((_Float16*)g.C)[(size_t)c * g.ldc + rr] = (_Float16)v;
      }
    }
  }
}

__global__ __launch_bounds__(256) void k_gemm_multi(
    GemmJob ja, GemmJob jb, GemmJob jc, const float* lacc, float* finout)
{
  int b = blockIdx.x;
  if (b < ja.nblk) { gemm128_body(b, ja); return; }
  b -= ja.nblk;
  if (b < jb.nblk) { gemm128_body(b, jb); return; }
  b -= jb.nblk;
  if (b < jc.nblk) { gemm128_body(b, jc); return; }
  if (finout && threadIdx.x == 0)
    finout[0] = lacc[0] * (1.0f / (4096.0f * 4096.0f));
}

// ================ score/softmax/aggregate (+ zcomb) dispatcher ==============

struct ScoreJob {
  _Float16* UY; const float* feat; const float* tsrc; const float* tngh;
  const int* idx; int rows;
};

__device__ void score_body(int row, const ScoreJob& J,
                           const float* __restrict__ freq,
                           const float* __restrict__ phase)
{
  __shared__ _Float16 fsh[20][136];
  __shared__ _Float16 tesh[20][136];
  __shared__ _Float16 ush[544];
  __shared__ float ssh[2][20];
  __shared__ float ash[2][20];
  __shared__ float dtsh[20];
  __shared__ int   msh[20];
  int tid = threadIdx.x;
  _Float16* UY = J.UY;

  if (tid < 20) {
    dtsh[tid] = J.tsrc[row] - J.tngh[(size_t)row * 20 + tid];
    msh[tid] = (J.idx[(size_t)row * 20 + tid] == 0);
  }
  if (tid < 130) {
    h4 v = *(const h4*)&UY[(size_t)row * 520 + tid * 4];
    int p4 = (tid < 65) ? tid : tid + 1;
    *(h4*)&ush[p4 * 4] = v;
  }
  const float4* fg = (const float4*)(J.feat + (size_t)row * 2560);
  for (int i = tid; i < 640; i += 256) {
    int j = i >> 5, c4 = i & 31;
    float4 v = fg[i];
    h4 hv = { (_Float16)v.x, (_Float16)v.y, (_Float16)v.z, (_Float16)v.w };
    *(h4*)&fsh[j][c4 * 4] = hv;
  }
  __syncthreads();
  for (int i = tid; i < 2560; i += 256) {
    int j = i >> 7, t = i & 127;
    tesh[j][t] = (_Float16)__cosf(dtsh[j] * freq[t] + phase[t]);
  }
  __syncthreads();

  int g = tid >> 4, li = tid & 15;
#pragma unroll
  for (int it = 0; it < 3; it++) {
    int t = it * 16 + g;
    int valid = (t < 40);
    int h = valid ? (t / 20) : 0;
    int j = valid ? (t % 20) : 0;
    float part = 0.f;
    if (valid) {
      const _Float16* xp = (li < 8) ? &fsh[j][li * 16] : &tesh[j][(li - 8) * 16];
      const _Float16* up = &ush[h * 264 + li * 16];
#pragma unroll
      for (int e = 0; e < 8; e++) {
        h2 a = *(const h2*)(xp + e * 2);
        h2 b = *(const h2*)(up + e * 2);
        part = __builtin_amdgcn_fdot2(a, b, part, false);
      }
    }
    for (int m = 8; m; m >>= 1) part += __shfl_xor(part, m, 16);
    if (valid && li == 0) ssh[h][j] = part + (float)ush[h * 264 + 256];
  }
  __syncthreads();

  if (tid < 64) {
    int head = tid >> 5, l2 = tid & 31;
    const float scale = 0.08838834764831845f; // 1/sqrt(128)
    float s = (l2 < 20) ? (msh[l2] ? -1e10f : ssh[head][l2] * scale) : -3.0e38f;
    float mx = s;
    for (int m = 16; m; m >>= 1) mx = fmaxf(mx, __shfl_xor(mx, m, 32));
    float e = (l2 < 20) ? __expf(s - mx) : 0.f;
    float sum = e;
    for (int m = 16; m; m >>= 1) sum += __shfl_xor(sum, m, 32);
    if (l2 < 20) ash[head][l2] = e / sum;
  }
  __syncthreads();

  {
    int p = tid;
    const _Float16* colp = (p < 128) ? &fsh[0][p] : &tesh[0][p - 128];
    float a0 = 0.f, a1 = 0.f;
#pragma unroll 5
    for (int j = 0; j < 20; j++) {
      float x = (float)colp[j * 136];
      a0 += ash[0][j] * x;
      a1 += ash[1][j] * x;
    }
    UY[(size_t)row * 520 + p] = (_Float16)a0;
    UY[(size_t)row * 520 + 260 + p] = (_Float16)a1;
  }
  if (tid < 8) {
    int p = (tid < 4) ? (256 + tid) : (512 + tid);
    _Float16 v = (_Float16)((tid == 0 || tid == 4) ? 1.f : 0.f);
    UY[(size_t)row * 520 + p] = v;
  }
}

__global__ __launch_bounds__(256, 8) void k_score_multi(
    ScoreJob ja, ScoreJob jb, const float* __restrict__ freq,
    const float* __restrict__ phase,
    const float* __restrict__ zp, _Float16* __restrict__ zh, int nzb)
{
  int b = blockIdx.x;
  if (b < ja.rows) { score_body(b, ja, freq, phase); return; }
  b -= ja.rows;
  if (b < jb.rows) { score_body(b, jb, freq, phase); return; }
  b -= jb.rows;
  if (b < nzb) {  // zcomb: sum 8 split-K partials -> f16
    int i = b * 256 + threadIdx.x;   // < 131072
    const f4* zp4 = (const f4*)zp;
    f4 s = (f4)0.f;
#pragma unroll
    for (int p = 0; p < 8; p++) {
      f4 v = zp4[(size_t)p * 131072 + i];
      s.x += v.x; s.y += v.y; s.z += v.z; s.w += v.w;
    }
    h4 o = { (_Float16)s.x, (_Float16)s.y, (_Float16)s.z, (_Float16)s.w };
    ((h4*)zh)[i] = o;
  }
}

// ============ tail (P-GEMM + LN + MergeLayer) + MFMA-loss dispatcher ========

struct TailJob {
  const _Float16* U; const _Float16* F; const float* fcb; const float* srcv;
  const float* lng; const float* lnb;
  const _Float16* m1w; const float* m1b;
  const _Float16* m2w; const float* m2b;
  float* outp; int nblk;
};

__device__ void tail_body(int blk, const TailJob& J, const float* __restrict__ te0)
{
  __shared__ _Float16 Ps[64][264];
  __shared__ _Float16 Ss[64][136];
  __shared__ float redS[64][4], redQ[64][4];
  __shared__ float mrow[64], rrow[64];
  int tid = threadIdx.x;
  int wv = tid >> 6, lane = tid & 63;
  int lr = lane & 15, lk = lane >> 4;
  int row0 = blk * 64;
  int n0 = wv * 64;

  {
    const float4* sg = (const float4*)(J.srcv + (size_t)row0 * 128);
    for (int i = tid; i < 2048; i += 256) {
      int rr = i >> 5, c4 = i & 31;
      float4 v = sg[i];
      h4 hv = { (_Float16)v.x, (_Float16)v.y, (_Float16)v.z, (_Float16)v.w };
      *(h4*)&Ss[rr][c4 * 4] = hv;
    }
  }

  f4 acc[4][4];
#pragma unroll
  for (int i = 0; i < 4; i++)
#pragma unroll
    for (int j = 0; j < 4; j++) acc[i][j] = (f4)0.f;
  for (int kt = 0; kt < 17; kt++) {
    int kb = kt * 32 + lk * 8;
    bool ok = (kb + 8 <= 520);
    h8 af[4], bf[4];
#pragma unroll
    for (int i = 0; i < 4; i++)
      af[i] = ok ? *(const h8*)&J.U[(size_t)(row0 + i * 16 + lr) * 520 + kb]
                 : (h8)(_Float16)0.f;
#pragma unroll
    for (int j = 0; j < 4; j++)
      bf[j] = ok ? *(const h8*)&J.F[(size_t)(n0 + j * 16 + lr) * 520 + kb]
                 : (h8)(_Float16)0.f;
#pragma unroll
    for (int i = 0; i < 4; i++)
#pragma unroll
      for (int j = 0; j < 4; j++)
        acc[i][j] = __builtin_amdgcn_mfma_f32_16x16x32_f16(af[i], bf[j], acc[i][j], 0, 0, 0);
  }

#pragma unroll
  for (int i = 0; i < 4; i++) {
#pragma unroll
    for (int r = 0; r < 4; r++) {
      int row_l = i * 16 + lk * 4 + r;
      float rs = 0.f, rq = 0.f;
#pragma unroll
      for (int j = 0; j < 4; j++) {
        int c = n0 + j * 16 + lr;
        float q = (c < 128) ? J.srcv[(size_t)(row0 + row_l) * 128 + c] : te0[c - 128];
        float v = acc[i][j][r] + J.fcb[c] + q;
        acc[i][j][r] = v;
        rs += v; rq += v * v;
      }
      for (int m = 8; m; m >>= 1) {
        rs += __shfl_xor(rs, m, 16);
        rq += __shfl_xor(rq, m, 16);
      }
      if (lr == 0) { redS[row_l][wv] = rs; redQ[row_l][wv] = rq; }
    }
  }
  __syncthreads();
  if (tid < 64) {
    float s4 = redS[tid][0] + redS[tid][1] + redS[tid][2] + redS[tid][3];
    float q4 = redQ[tid][0] + redQ[tid][1] + redQ[tid][2] + redQ[tid][3];
    float mean = s4 * (1.0f / 256.0f);
    float var = q4 * (1.0f / 256.0f) - mean * mean;
    mrow[tid] = mean;
    rrow[tid] = rsqrtf(var + 1e-5f);
  }
  __syncthreads();
#pragma unroll
  for (int i = 0; i < 4; i++) {
#pragma unroll
    for (int r = 0; r < 4; r++) {
      int row_l = i * 16 + lk * 4 + r;
      float mean = mrow[row_l], rstd = rrow[row_l];
#pragma unroll
      for (int j = 0; j < 4; j++) {
        int c = n0 + j * 16 + lr;
        Ps[row_l][c] = (_Float16)((acc[i][j][r] - mean) * rstd * J.lng[c] + J.lnb[c]);
      }
    }
  }
  __syncthreads();

  int wm = wv >> 1, wn = wv & 1;
  f4 a2[2][4];
#pragma unroll
  for (int i = 0; i < 2; i++)
#pragma unroll
    for (int j = 0; j < 4; j++) a2[i][j] = (f4)0.f;
  for (int kk = 0; kk < 12; kk++) {
    int kb = kk * 32 + lk * 8;
    h8 af[2], bf[4];
#pragma unroll
    for (int i = 0; i < 2; i++) {
      int rl = wm * 32 + i * 16 + lr;
      af[i] = (kb < 256) ? *(const h8*)&Ps[rl][kb] : *(const h8*)&Ss[rl][kb - 256];
    }
#pragma unroll
    for (int j = 0; j < 4; j++)
      bf[j] = *(const h8*)&J.m1w[(size_t)(wn * 64 + j * 16 + lr) * 384 + kb];
#pragma unroll
    for (int i = 0; i < 2; i++)
#pragma unroll
      for (int j = 0; j < 4; j++)
        a2[i][j] = __builtin_amdgcn_mfma_f32_16x16x32_f16(af[i], bf[j], a2[i][j], 0, 0, 0);
  }
  __syncthreads();
#pragma unroll
  for (int i = 0; i < 2; i++) {
#pragma unroll
    for (int j = 0; j < 4; j++) {
      int c = wn * 64 + j * 16 + lr;
      float bz = J.m1b[c];
#pragma unroll
      for (int r = 0; r < 4; r++) {
        float v = a2[i][j][r] + bz;
        if (v < 0.f) v = 0.f;
        Ss[wm * 32 + i * 16 + lk * 4 + r][c] = (_Float16)v;
      }
    }
  }
  __syncthreads();

  f4 a3[2][4];
#pragma unroll
  for (int i = 0; i < 2; i++)
#pragma unroll
    for (int j = 0; j < 4; j++) a3[i][j] = (f4)0.f;
#pragma unroll
  for (int kk = 0; kk < 4; kk++) {
    int kb = kk * 32 + lk * 8;
    h8 af[2], bf[4];
#pragma unroll
    for (int i = 0; i < 2; i++)
      af[i] = *(const h8*)&Ss[wm * 32 + i * 16 + lr][kb];
#pragma unroll
    for (int j = 0; j < 4; j++)
      bf[j] = *(const h8*)&J.m2w[(size_t)(wn * 64 + j * 16 + lr) * 128 + kb];
#pragma unroll
    for (int i = 0; i < 2; i++)
#pragma unroll
      for (int j = 0; j < 4; j++)
        a3[i][j] = __builtin_amdgcn_mfma_f32_16x16x32_f16(af[i], bf[j], a3[i][j], 0, 0, 0);
  }
#pragma unroll
  for (int j = 0; j < 4; j++) {
    int c = wn * 64 + j * 16 + lr;
    float bz = J.m2b[c];
#pragma unroll
    for (int i = 0; i < 2; i++) {
#pragma unroll
      for (int r = 0; r < 4; r++) {
        int rl = wm * 32 + i * 16 + lk * 4 + r;
        J.outp[(size_t)(row0 + rl) * 128 + c] = a3[i][j][r] + bz;
      }
    }
  }
}

__device__ void loss_body(int b, const _Float16* __restrict__ z,
                          const float* __restrict__ adj, float* __restrict__ acc)
{
  int bi = b & 31, bj = b >> 5;
  int tid = threadIdx.x;
  int wv = tid >> 6, lane = tid & 63;
  int wm = wv >> 1, wn = wv & 1;
  int lr = lane & 15, lk = lane >> 4;
  int row0 = bi * 128 + wm * 64;
  int col0 = bj * 128 + wn * 64;

  f4 accf[4][4];
#pragma unroll
  for (int i = 0; i < 4; i++)
#pragma unroll
    for (int j = 0; j < 4; j++) accf[i][j] = (f4)0.f;

#pragma unroll
  for (int kk = 0; kk < 4; kk++) {
    int ko = kk * 32 + lk * 8;
    h8 af[4], bf[4];
#pragma unroll
    for (int i = 0; i < 4; i++)
      af[i] = *(const h8*)&z[(size_t)(row0 + i * 16 + lr) * 128 + ko];
#pragma unroll
    for (int j = 0; j < 4; j++)
      bf[j] = *(const h8*)&z[(size_t)(col0 + j * 16 + lr) * 128 + ko];
#pragma unroll
    for (int i = 0; i < 4; i++)
#pragma unroll
      for (int j = 0; j < 4; j++)
        accf[i][j] = __builtin_amdgcn_mfma_f32_16x16x32_f16(af[i], bf[j], accf[i][j], 0, 0, 0);
  }

  float lsum = 0.f;
#pragma unroll
  for (int i = 0; i < 4; i++) {
    int rbase = row0 + i * 16 + lk * 4;
#pragma unroll
    for (int r = 0; r < 4; r++) {
      const float* arow = adj + (size_t)(rbase + r) * 4096;
#pragma unroll
      for (int j = 0; j < 4; j++) {
        float x = accf[i][j][r];
        float s = 1.0f / (1.0f + __expf(-x));
        float d = arow[col0 + j * 16 + lr] - s;
        lsum += d * d;
      }
    }
  }
  for (int m = 32; m; m >>= 1) lsum += __shfl_xor(lsum, m, 64);
  if (lane == 0) atomicAdd(acc, lsum);
}

__global__ __launch_bounds__(256) void k_tail_loss(
    TailJob ja, TailJob jb, const float* __restrict__ te0,
    const _Float16* __restrict__ z, const float* __restrict__ adj,
    float* __restrict__ lacc, int nloss)
{
  int b = blockIdx.x;
  if (b < ja.nblk) { tail_body(b, ja, te0); return; }
  b -= ja.nblk;
  if (b < jb.nblk) { tail_body(b, jb, te0); return; }
  b -= jb.nblk;
  if (b < nloss) loss_body(b, z, adj, lacc);
}

// ---------------------------------------------------------------------------

extern "C" void kernel_launch(void* const* d_in, const int* in_sizes, int n_in,
                              void* d_out, int out_size, void* d_ws, size_t ws_size,
                              hipStream_t stream) {
  const float* src_feat  = (const float*)d_in[0];
  const float* src_t     = (const float*)d_in[1];
  const int*   ngh1_idx  = (const int*)d_in[2];
  const float* ngh1_t    = (const float*)d_in[3];
  const float* ngh1_feat = (const float*)d_in[4];
  const int*   ngh2_idx  = (const int*)d_in[5];
  const float* ngh2_t    = (const float*)d_in[6];
  const float* ngh2_feat = (const float*)d_in[7];
  const float* ae_x      = (const float*)d_in[8];
  const float* ae_adj    = (const float*)d_in[9];
  const float* W_lin     = (const float*)d_in[10];
  const float* b_lin     = (const float*)d_in[11];
  const float* freq      = (const float*)d_in[12];
  const float* phase     = (const float*)d_in[13];
  const float* wq        = (const float*)d_in[14];
  const float* wk        = (const float*)d_in[15];
  const float* wvp       = (const float*)d_in[16];
  const float* fcw       = (const float*)d_in[17];
  const float* fcb       = (const float*)d_in[18];
  const float* lng       = (const float*)d_in[19];
  const float* lnb       = (const float*)d_in[20];
  const float* m1w       = (const float*)d_in[21];
  const float* m1b       = (const float*)d_in[22];
  const float* m2w       = (const float*)d_in[23];
  const float* m2b       = (const float*)d_in[24];
  const float* W_gc      = (const float*)d_in[25];
  const float* b_gc      = (const float*)d_in[26];
  float* out = (float*)d_out;

  const int NB = 2048, NA = 40960;

  char* w = (char*)d_ws;
  size_t off = 0;
  auto alloc = [&](size_t bytes) -> void* {
    void* p = (void*)(w + off);
    off += (bytes + 255) & ~(size_t)255;
    return p;
  };
  float* te0    = (float*)alloc(128 * 4);
  float* linS   = (float*)alloc((size_t)NB * 128 * 4);
  float* lin1   = (float*)alloc((size_t)NA * 128 * 4);
  float* src_l1 = (float*)alloc((size_t)NB * 128 * 4);
  float* ngh_l1 = (float*)alloc((size_t)NA * 128 * 4);
  float* Mb     = (float*)alloc((size_t)4 * 32768 * 4);
  float* cbf    = (float*)alloc(4 * 256 * 4);
  _Float16* SWh = (_Float16*)alloc((size_t)3 * 520 * 128 * 2);
  float* cbU    = (float*)alloc(3 * 520 * 4);
  float* OW     = (float*)alloc((size_t)3 * 2 * 128 * 260 * 4);
  _Float16* Fh  = (_Float16*)alloc((size_t)3 * 256 * 520 * 2);
  _Float16* Wlinh = (_Float16*)alloc(16384 * 2);
  _Float16* m1wh  = (_Float16*)alloc((size_t)2 * 128 * 384 * 2);
  _Float16* m2wh  = (_Float16*)alloc((size_t)2 * 128 * 128 * 2);
  _Float16* WgcTh = (_Float16*)alloc(16384 * 2);
  _Float16* xwTh  = (_Float16*)alloc((size_t)4096 * 128 * 2);
  float* zpart    = (float*)alloc((size_t)8 * 4096 * 128 * 4);
  _Float16* zh    = (_Float16*)alloc((size_t)4096 * 128 * 2);
  float* lacc     = (float*)alloc(256);
  _Float16* UbufA = (_Float16*)alloc((size_t)NA * 520 * 2);
  _Float16* UbufB = (_Float16*)alloc((size_t)NB * 520 * 2);
  _Float16* UbufC = (_Float16*)alloc((size_t)NB * 520 * 2);

  // L1: independent prep (4 + 512 + 780 + 640 = 1936 blocks)
  k_prep_a<<<1936, 256, 0, stream>>>(phase, wq, wk, wvp, W_lin, b_lin, m1w, m2w,
                                     W_gc, te0, cbf, Mb, OW, Wlinh, m1wh, m2wh,
                                     WgcTh, lacc);
  // L2: dependent prep (780 + 1560 = 2340)
  k_prep_b<<<2340, 256, 0, stream>>>(Mb, cbf, W_lin, b_lin, fcw, OW, SWh, cbU, Fh);

  GemmJob j0 = {};

  // L3: {linS, lin1, xwT}
  GemmJob jLinS = { src_feat,  Wlinh, b_lin,   linS,         128, 128, 128,
                    2048, 128, 128, 0, 128, 16, 1, 16 };
  GemmJob jLin1 = { ngh1_feat, Wlinh, b_lin,   lin1,         128, 128, 128,
                    40960, 128, 128, 0, 128, 320, 1, 320 };
  GemmJob jXwT  = { ae_x,      WgcTh, nullptr, (float*)xwTh, 128, 128, 4096,
                    4096, 128, 128, 2, 128, 32, 1, 32 };
  k_gemm_multi<<<368, 256, 0, stream>>>(jLinS, jLin1, jXwT, nullptr, nullptr);

  // L4: {U-A, U-B, zb split-K=8}
  GemmJob jUA = { lin1, SWh,              cbU,       (float*)UbufA, 128, 128, 520,
                  40960, 520, 128, 1, 128, 320, 5, 1600 };
  GemmJob jUB = { linS, SWh + 520 * 128,  cbU + 520, (float*)UbufB, 128, 128, 520,
                  2048, 520, 128, 1, 128, 16, 5, 80 };
  GemmJob jZB = { ae_adj, xwTh, b_gc, zpart, 4096, 4096, 128,
                  4096, 128, 4096, 0, 512, 32, 1, 256 };
  k_gemm_multi<<<1936, 256, 0, stream>>>(jUA, jUB, jZB, nullptr, nullptr);

  // L5: {score-A, score-B, zcomb}
  ScoreJob sA = { UbufA, ngh2_feat, ngh1_t, ngh2_t, ngh2_idx, NA };
  ScoreJob sB = { UbufB, lin1,      src_t,  ngh1_t, ngh1_idx, NB };
  k_score_multi<<<NA + NB + 512, 256, 0, stream>>>(sA, sB, freq, phase,
                                                   zpart, zh, 512);

  // L6: {tail-A, tail-B, loss}
  TailJob tA = { UbufA, Fh,             fcb, lin1, lng, lnb,
                 m1wh, m1b, m2wh, m2b, ngh_l1, NA / 64 };
  TailJob tB = { UbufB, Fh + 256 * 520, fcb, linS, lng, lnb,
                 m1wh, m1b, m2wh, m2b, src_l1, NB / 64 };
  k_tail_loss<<<NA / 64 + NB / 64 + 1024, 256, 0, stream>>>(
      tA, tB, te0, zh, ae_adj, lacc, 1024);

  // L7: {U-C, final loss write}
  GemmJob jUC = { src_l1, SWh + 2 * 520 * 128, cbU + 2 * 520, (float*)UbufC,
                  128, 128, 520, 2048, 520, 128, 1, 128, 16, 5, 80 };
  k_gemm_multi<<<81, 256, 0, stream>>>(jUC, j0, j0, lacc, out + (size_t)NB * 128);

  // L8: {score-C}
  ScoreJob sC = { UbufC, ngh_l1, src_t, ngh1_t, ngh1_idx, NB };
  ScoreJob s0 = {};
  k_score_multi<<<NB, 256, 0, stream>>>(sC, s0, freq, phase, nullptr, nullptr, 0);

  // L9: {tail-C} -> d_out
  TailJob tC = { UbufC, Fh + 2 * 256 * 520, fcb + 256, src_l1, lng + 256, lnb + 256,
                 m1wh + 128 * 384, m1b + 128, m2wh + 128 * 128, m2b + 128,
                 out, NB / 64 };
  TailJob t0 = {};
  k_tail_loss<<<NB / 64, 256, 0, stream>>>(tC, t0, te0, nullptr, nullptr,
                                           nullptr, 0);
}